// Round 17
// baseline (1779.918 us; speedup 1.0000x reference)
//
#include <hip/hip_runtime.h>
#include <hip/hip_bf16.h>

#define NNODES 100000
#define HIDC 256
#define NFEAT 9
#define VOCABS 128
#define BFD 128        // bases output dim
#define NCOMB 96       // heads*bases*aggs
#define NGR 5000
#define LAYERSN 4
#define EPSV 1e-5f
#define SCHUNK 1024    // scan chunk
#define NPP 16         // rows per block in pooling
#define NTILES 14      // 224/16 output tiles (8 bases + 6 comb)
#define AGGBLK 2048    // agg grid
#define PBL (NTILES * 8 * 64)   // B fragments per layer
#define NBUK 32        // scatter buckets
#define BDIV 3125      // nodes per bucket
#define SC2K 64        // blocks per bucket in pass B
#define RPBH 20        // rows per block in head GEMM
#define OST 232        // LDS out-stage row stride (bf16), 16B-aligned rows

typedef __hip_bfloat16 bf16;
typedef __attribute__((ext_vector_type(8))) short sh8;
typedef __attribute__((ext_vector_type(4))) float fx4;

__device__ __forceinline__ float b2f(bf16 v) { return __bfloat162float(v); }
__device__ __forceinline__ bf16 f2b(float v) { return __float2bfloat16(v); }
__device__ __forceinline__ float ldf(const float* p) { return *p; }
__device__ __forceinline__ float ldf(const bf16* p) { return b2f(*p); }
__device__ __forceinline__ float2 unpk(unsigned u) {
    return make_float2(__uint_as_float(u << 16), __uint_as_float(u & 0xFFFF0000u));
}
__device__ __forceinline__ unsigned pack2bf(float a, float b) {
    unsigned ua = __float_as_uint(a), ub = __float_as_uint(b);
    ua = (ua + 0x7FFFu + ((ua >> 16) & 1u)) >> 16;
    ub = (ub + 0x7FFFu + ((ub >> 16) & 1u)) >> 16;
    return ua | (ub << 16);
}

// 0. sentinel
__global__ __launch_bounds__(256) void k_sentinel(float* out, int n, float val) {
    int i = blockIdx.x * 256 + threadIdx.x;
    if (i < n) out[i] = val;
}

// 2a. histogram of dst
__global__ __launch_bounds__(256) void k_hist(const int* __restrict__ dst,
                                              int* __restrict__ counts, int E) {
    int e = blockIdx.x * 256 + threadIdx.x;
    if (e < E) atomicAdd(&counts[dst[e]], 1);
}

__global__ __launch_bounds__(256) void k_scansum(const int* __restrict__ counts,
                                                 int* __restrict__ btot, int n) {
    __shared__ int sh[256];
    int b = blockIdx.x, t = threadIdx.x;
    int base = b * SCHUNK;
    int s = 0;
#pragma unroll
    for (int k = 0; k < 4; ++k) {
        int i = base + t + k * 256;
        if (i < n) s += counts[i];
    }
    sh[t] = s;
    __syncthreads();
    for (int st = 128; st > 0; st >>= 1) {
        if (t < st) sh[t] += sh[t + st];
        __syncthreads();
    }
    if (t == 0) btot[b] = sh[0];
}

__global__ void k_scansmall(const int* __restrict__ btot, int* __restrict__ boff, int nb) {
    if (threadIdx.x == 0 && blockIdx.x == 0) {
        int a = 0;
        for (int i = 0; i < nb; ++i) { boff[i] = a; a += btot[i]; }
    }
}

// 2b-3. per-chunk scan -> rowptr AND cursor
__global__ __launch_bounds__(256) void k_scanapply(const int* __restrict__ counts,
                                                   const int* __restrict__ boff,
                                                   int* __restrict__ rowptr,
                                                   int* __restrict__ cursor, int n) {
    __shared__ int sh[256];
    int b = blockIdx.x, t = threadIdx.x;
    int base = b * SCHUNK + t * 4;
    int c0 = (base + 0 < n) ? counts[base + 0] : 0;
    int c1 = (base + 1 < n) ? counts[base + 1] : 0;
    int c2 = (base + 2 < n) ? counts[base + 2] : 0;
    int c3 = (base + 3 < n) ? counts[base + 3] : 0;
    int s0 = c0, s1 = s0 + c1, s2 = s1 + c2, s3 = s2 + c3;
    sh[t] = s3;
    __syncthreads();
    for (int st = 1; st < 256; st <<= 1) {
        int v = (t >= st) ? sh[t - st] : 0;
        __syncthreads();
        sh[t] += v;
        __syncthreads();
    }
    int excl = sh[t] - s3 + boff[b];
    if (base + 0 < n) { rowptr[base + 1] = excl + s0; cursor[base + 0] = excl; }
    if (base + 1 < n) { rowptr[base + 2] = excl + s1; cursor[base + 1] = excl + s0; }
    if (base + 2 < n) { rowptr[base + 3] = excl + s2; cursor[base + 2] = excl + s1; }
    if (base + 3 < n) { rowptr[base + 4] = excl + s3; cursor[base + 3] = excl + s2; }
    if (b == 0 && t == 0) rowptr[0] = 0;
}

// 2e. bucket cursors
__global__ void k_binit(const int* __restrict__ rowptr, int* __restrict__ gcur) {
    int b = threadIdx.x;
    if (b < NBUK) gcur[b] = rowptr[b * BDIV];
}

// 2f. pass A: partition edges into ebuf by dst bucket
__global__ __launch_bounds__(256) void k_bucket(const int* __restrict__ src,
                                                const int* __restrict__ dst,
                                                int* __restrict__ gcur,
                                                uint2* __restrict__ ebuf, int E) {
    __shared__ int cnt[NBUK], base[NBUK], off[NBUK];
    int tid = threadIdx.x;
    if (tid < NBUK) { cnt[tid] = 0; off[tid] = 0; }
    __syncthreads();
    int d[4], s[4], bk[4];
    int e0 = blockIdx.x * 1024;
#pragma unroll
    for (int k = 0; k < 4; ++k) {
        int e = e0 + tid + k * 256;
        if (e < E) {
            d[k] = dst[e]; s[k] = src[e];
            bk[k] = d[k] / BDIV;
            atomicAdd(&cnt[bk[k]], 1);
        } else bk[k] = -1;
    }
    __syncthreads();
    if (tid < NBUK && cnt[tid] > 0) base[tid] = atomicAdd(&gcur[tid], cnt[tid]);
    __syncthreads();
#pragma unroll
    for (int k = 0; k < 4; ++k) {
        if (bk[k] >= 0) {
            int sl = base[bk[k]] + atomicAdd(&off[bk[k]], 1);
            ebuf[sl] = make_uint2((unsigned)d[k], (unsigned)s[k]);
        }
    }
}

// 2g. pass B: scatter within buckets
__global__ __launch_bounds__(256) void k_scatter2(const uint2* __restrict__ ebuf,
                                                  const int* __restrict__ rowptr,
                                                  int* __restrict__ cursor,
                                                  int* __restrict__ csr) {
    int bk = blockIdx.x & (NBUK - 1);
    int chunk = blockIdx.x >> 5;
    int lo = rowptr[bk * BDIV];
    int nhi = (bk + 1) * BDIV; if (nhi > NNODES) nhi = NNODES;
    int hi = rowptr[nhi];
    for (int e = lo + chunk * 256 + threadIdx.x; e < hi; e += SC2K * 256) {
        uint2 p = ebuf[e];
        int pos = atomicAdd(&cursor[p.x], 1);
        csr[pos] = (int)p.y;
    }
}

// 3a. pack W of ALL layers into MFMA B-fragment order
__global__ __launch_bounds__(256) void k_packB4(const float* __restrict__ basesW,
                                                const float* __restrict__ combW,
                                                bf16* __restrict__ Bp4) {
    int tid = blockIdx.x * 256 + threadIdx.x;
    if (tid >= LAYERSN * PBL) return;
    int layer = tid / PBL;
    int rem = tid % PBL;
    int l = rem & 63;
    int q = (rem >> 6) & 7;
    int t = rem >> 9;
    int n = t * 16 + (l & 15);
    int k0 = q * 32 + (l >> 4) * 8;
    const float* Wb = basesW + (size_t)layer * HIDC * BFD;
    const float* Wc = combW + (size_t)layer * HIDC * NCOMB;
    short out[8];
#pragma unroll
    for (int i = 0; i < 8; ++i) {
        int k = k0 + i;
        float v = (n < BFD) ? Wb[k * BFD + n] : Wc[k * NCOMB + (n - BFD)];
        unsigned u = __float_as_uint(v);
        out[i] = (short)((u + 0x7FFFu + ((u >> 16) & 1u)) >> 16);
    }
    *(sh8*)(Bp4 + (size_t)tid * 8) = *(sh8*)out;
}

// 3b. MFMA node GEMM (64 rows/block, 4 waves), dynamic LDS.
//     MODE 0: 35072 B (A-stage + xsh). MODE 1: 32768 B exactly -> 5 blocks/CU.
template <int MODE>
__global__ __launch_bounds__(256) void k_gemm_mfma(bf16* __restrict__ h,
                                                   const bf16* __restrict__ Bp,
                                                   const float* __restrict__ cb,
                                                   bf16* __restrict__ bases,
                                                   bf16* __restrict__ wco,
                                                   const bf16* __restrict__ convp,
                                                   const float* __restrict__ ss,
                                                   const int* __restrict__ x,
                                                   const float* __restrict__ emb) {
    extern __shared__ char smem[];
    unsigned* ldsA = (unsigned*)smem;                 // 32768 B
    int* xsh = (int*)(smem + 32768);                  // MODE 0 only: 2304 B
    int tid = threadIdx.x;
    size_t blk = blockIdx.x;
    if (MODE == 0) {
        for (int i = tid; i < 64 * NFEAT; i += 256) {
            int row = i / NFEAT;
            size_t rg = blk * 64 + row;
            xsh[i] = (rg < NNODES) ? x[rg * NFEAT + (i % NFEAT)] : 0;
        }
        __syncthreads();
    }
    // ---- stage h -> LDS (uint4 = 8 bf16 per thread per iter) ----
#pragma unroll
    for (int it = 0; it < 8; ++it) {
        int p = tid + it * 256;
        int row = p >> 5, g4 = p & 31;
        size_t rg = blk * 64 + row;
        uint4 word4 = make_uint4(0u, 0u, 0u, 0u);
        if (rg < NNODES) {
            int c0 = g4 * 8;
            unsigned res[4];
            if (MODE == 0) {
                float a[8];
#pragma unroll
                for (int q = 0; q < 8; ++q) a[q] = 0.f;
#pragma unroll
                for (int f = 0; f < NFEAT; ++f) {
                    const float* ep = emb + ((size_t)(f * VOCABS + xsh[row * NFEAT + f])) * HIDC + c0;
                    float4 e0 = *(const float4*)ep;
                    float4 e1 = *(const float4*)(ep + 4);
                    a[0] += e0.x; a[1] += e0.y; a[2] += e0.z; a[3] += e0.w;
                    a[4] += e1.x; a[5] += e1.y; a[6] += e1.z; a[7] += e1.w;
                }
#pragma unroll
                for (int q = 0; q < 4; ++q) res[q] = pack2bf(a[2 * q], a[2 * q + 1]);
            } else {
                uint4 hv = ((const uint4*)h)[rg * 32 + g4];
                uint4 cv = ((const uint4*)convp)[rg * 32 + g4];
                unsigned hw[4] = {hv.x, hv.y, hv.z, hv.w};
                unsigned cw[4] = {cv.x, cv.y, cv.z, cv.w};
#pragma unroll
                for (int q = 0; q < 4; ++q) {
                    float2 hf = unpk(hw[q]);
                    float2 cf = unpk(cw[q]);
                    float2 sc = *(const float2*)&ss[(g4 * 8) + 2 * q];
                    float2 sb = *(const float2*)&ss[HIDC + (g4 * 8) + 2 * q];
                    float a0 = hf.x + fmaxf(cf.x * sc.x + sb.x, 0.f);
                    float a1 = hf.y + fmaxf(cf.y * sc.y + sb.y, 0.f);
                    res[q] = pack2bf(a0, a1);
                }
            }
            word4 = make_uint4(res[0], res[1], res[2], res[3]);
            ((uint4*)h)[rg * 32 + g4] = word4;
        }
        ((uint4*)ldsA)[(row * 32 + g4) ^ (row & 7)] = word4;
    }
    __syncthreads();
    // ---- load A fragments ----
    int w = tid >> 6, l = tid & 63;
    int r = 16 * w + (l & 15);
    sh8 af[8];
    const char* lb = (const char*)ldsA;
#pragma unroll
    for (int q = 0; q < 8; ++q) {
        int byte = (r * 512 + q * 64 + (l >> 4) * 16) ^ ((r & 7) << 4);
        af[q] = *(const sh8*)(lb + byte);
    }
    __syncthreads();
    // ---- MFMA per tile + bf16 restage into LDS ----
    bf16* outl = (bf16*)smem;        // [64][OST] bf16, 29.7 KB
    const sh8* bp8 = (const sh8*)Bp;
#pragma unroll
    for (int t = 0; t < NTILES; ++t) {
        fx4 acc = (fx4){0.f, 0.f, 0.f, 0.f};
#pragma unroll
        for (int q = 0; q < 8; ++q) {
            acc = __builtin_amdgcn_mfma_f32_16x16x32_bf16(
                af[q], bp8[(t * 8 + q) * 64 + l], acc, 0, 0, 0);
        }
        int colb = t * 16 + (l & 15);
        float bias_v = (t >= 8) ? cb[colb - BFD] : 0.f;
#pragma unroll
        for (int j = 0; j < 4; ++j) {
            int rl = 16 * w + (l >> 4) * 4 + j;
            outl[rl * OST + colb] = f2b(acc[j] + bias_v);
        }
    }
    __syncthreads();
    // ---- coalesced global writes ----
    for (int i = tid; i < 64 * 16; i += 256) {
        int row = i >> 4, c4 = i & 15;
        size_t rg = blk * 64 + row;
        if (rg < NNODES)
            ((uint4*)bases)[rg * 16 + c4] = *(const uint4*)&outl[row * OST + c4 * 8];
    }
    for (int i = tid; i < 64 * 12; i += 256) {
        int row = i / 12, c4 = i % 12;
        size_t rg = blk * 64 + row;
        if (rg < NNODES)
            ((uint4*)wco)[rg * 12 + c4] = *(const uint4*)&outl[row * OST + BFD + c4 * 8];
    }
}

// 4. CSR aggregation + einsum + fused BN-stat partials. v6 + rowptr prefetch.
template <typename TW>
__global__ __launch_bounds__(256) void k_agg(const int* __restrict__ rowptr,
                                             const int* __restrict__ csr,
                                             const uint4* __restrict__ b4,
                                             const TW* __restrict__ wco,
                                             const float* __restrict__ bias,
                                             bf16* __restrict__ conv,
                                             float* __restrict__ partials) {
    __shared__ float agg[8][3][BFD];
    __shared__ float red[512];
    int tid = threadIdx.x;
    int g = tid >> 5, cl = tid & 31;
    int sub = cl >> 4;
    int ln16 = cl & 15;
    red[tid] = 0.f;
    red[tid + 256] = 0.f;
    __syncthreads();
    int hh = cl >> 2;
    int dbase = 8 * (cl & 3);
    float bb[8];
#pragma unroll
    for (int j = 0; j < 8; ++j) bb[j] = bias[8 * cl + j];
    float sts[8], sts2[8];
#pragma unroll
    for (int j = 0; j < 8; ++j) { sts[j] = 0.f; sts2[j] = 0.f; }
    int n0 = blockIdx.x * 8 + g;
    int pr0 = 0, pr1 = 0;
    if (n0 < NNODES) { pr0 = rowptr[n0]; pr1 = rowptr[n0 + 1]; }
    for (int n = n0; n < NNODES; n += AGGBLK * 8) {
        int r0 = pr0, r1 = pr1;
        int n2 = n + AGGBLK * 8;
        if (n2 < NNODES) { pr0 = rowptr[n2]; pr1 = rowptr[n2 + 1]; }
        float s0 = 0.f, s1 = 0.f, s2 = 0.f, s3 = 0.f;
        float s4 = 0.f, s5 = 0.f, s6 = 0.f, s7 = 0.f;
        float m0 = -INFINITY, m1 = -INFINITY, m2 = -INFINITY, m3 = -INFINITY;
        float m4 = -INFINITY, m5 = -INFINITY, m6 = -INFINITY, m7 = -INFINITY;
        int e = r0;
#define ACCU4(v) { float f0 = __uint_as_float((v).x << 16);            \
                   float f1 = __uint_as_float((v).x & 0xFFFF0000u);    \
                   float f2 = __uint_as_float((v).y << 16);            \
                   float f3 = __uint_as_float((v).y & 0xFFFF0000u);    \
                   float f4 = __uint_as_float((v).z << 16);            \
                   float f5 = __uint_as_float((v).z & 0xFFFF0000u);    \
                   float f6 = __uint_as_float((v).w << 16);            \
                   float f7 = __uint_as_float((v).w & 0xFFFF0000u);    \
                   s0 += f0; s1 += f1; s2 += f2; s3 += f3;             \
                   s4 += f4; s5 += f5; s6 += f6; s7 += f7;             \
                   m0 = fmaxf(m0, f0); m1 = fmaxf(m1, f1);             \
                   m2 = fmaxf(m2, f2); m3 = fmaxf(m3, f3);             \
                   m4 = fmaxf(m4, f4); m5 = fmaxf(m5, f5);             \
                   m6 = fmaxf(m6, f6); m7 = fmaxf(m7, f7); }
        for (; e + 8 <= r1; e += 8) {
            int i0 = csr[e + 0 + sub], i1 = csr[e + 2 + sub];
            int i2 = csr[e + 4 + sub], i3 = csr[e + 6 + sub];
            uint4 v0 = b4[(size_t)i0 * 16 + ln16];
            uint4 v1 = b4[(size_t)i1 * 16 + ln16];
            uint4 v2 = b4[(size_t)i2 * 16 + ln16];
            uint4 v3 = b4[(size_t)i3 * 16 + ln16];
            ACCU4(v0) ACCU4(v1) ACCU4(v2) ACCU4(v3)
        }
        for (; e + 2 <= r1; e += 2) {
            uint4 v = b4[(size_t)csr[e + sub] * 16 + ln16];
            ACCU4(v)
        }
        if (e < r1 && sub == 0) {
            uint4 v = b4[(size_t)csr[e] * 16 + ln16];
            ACCU4(v)
        }
#undef ACCU4
        s0 += __shfl_xor(s0, 16); s1 += __shfl_xor(s1, 16);
        s2 += __shfl_xor(s2, 16); s3 += __shfl_xor(s3, 16);
        s4 += __shfl_xor(s4, 16); s5 += __shfl_xor(s5, 16);
        s6 += __shfl_xor(s6, 16); s7 += __shfl_xor(s7, 16);
        m0 = fmaxf(m0, __shfl_xor(m0, 16)); m1 = fmaxf(m1, __shfl_xor(m1, 16));
        m2 = fmaxf(m2, __shfl_xor(m2, 16)); m3 = fmaxf(m3, __shfl_xor(m3, 16));
        m4 = fmaxf(m4, __shfl_xor(m4, 16)); m5 = fmaxf(m5, __shfl_xor(m5, 16));
        m6 = fmaxf(m6, __shfl_xor(m6, 16)); m7 = fmaxf(m7, __shfl_xor(m7, 16));
        if (sub == 0) {
            float inv = 1.0f / (float)(r1 - r0);
            int cb2 = ln16 * 8;
            *(float4*)&agg[g][0][cb2]     = make_float4(s0, s1, s2, s3);
            *(float4*)&agg[g][0][cb2 + 4] = make_float4(s4, s5, s6, s7);
            *(float4*)&agg[g][1][cb2]     = make_float4(s0 * inv, s1 * inv, s2 * inv, s3 * inv);
            *(float4*)&agg[g][1][cb2 + 4] = make_float4(s4 * inv, s5 * inv, s6 * inv, s7 * inv);
            *(float4*)&agg[g][2][cb2]     = make_float4(m0, m1, m2, m3);
            *(float4*)&agg[g][2][cb2 + 4] = make_float4(m4, m5, m6, m7);
        }
        const TW* wp = &wco[(size_t)n * NCOMB + hh * 12];
        float wv[12];
#pragma unroll
        for (int k = 0; k < 12; ++k) wv[k] = ldf(&wp[k]);
        float o[8];
#pragma unroll
        for (int j = 0; j < 8; ++j) {
            int d = dbase + j;
            float a = 0.f;
#pragma unroll
            for (int b = 0; b < 4; ++b) {
                a += wv[b] * agg[g][0][b * 32 + d];
                a += wv[4 + b] * agg[g][1][b * 32 + d];
                a += wv[8 + b] * agg[g][2][b * 32 + d];
            }
            a += bb[j];
            o[j] = a;
            sts[j] += a;
            sts2[j] += a * a;
        }
        uint4 cv = make_uint4(pack2bf(o[0], o[1]), pack2bf(o[2], o[3]),
                              pack2bf(o[4], o[5]), pack2bf(o[6], o[7]));
        ((uint4*)conv)[(size_t)n * 32 + cl] = cv;
    }
#pragma unroll
    for (int j = 0; j < 8; ++j) {
        atomicAdd(&red[8 * cl + j], sts[j]);
        atomicAdd(&red[256 + 8 * cl + j], sts2[j]);
    }
    __syncthreads();
    partials[(size_t)blockIdx.x * 512 + tid] = red[tid];
    partials[(size_t)blockIdx.x * 512 + 256 + tid] = red[tid + 256];
}

// 4b. reduce partials -> sums[512]
__global__ __launch_bounds__(256) void k_redstats(const float* __restrict__ partials,
                                                  float* __restrict__ sums) {
    int g = blockIdx.x * 256 + threadIdx.x;
    int j = g & 511;
    int chunk = g >> 9;
    float s = 0.f;
    for (int pb = chunk * 256; pb < (chunk + 1) * 256; ++pb)
        s += partials[(size_t)pb * 512 + j];
    atomicAdd(&sums[j], s);
}

// 6. BN finalize
template <int C>
__global__ void k_bnfin(const float* __restrict__ sums, const float* __restrict__ g,
                        const float* __restrict__ b, float nrows, float* __restrict__ ss) {
    int c = threadIdx.x;
    float mu = sums[c] / nrows;
    float var = sums[C + c] / nrows - mu * mu;
    float rstd = rsqrtf(fmaxf(var, 0.f) + EPSV);
    float sc = rstd * g[c];
    ss[c] = sc;
    ss[C + c] = b[c] - mu * sc;
}

// 8. pooling with FUSED final-layer BN-apply+ReLU+residual; uint4 loads.
//    tid = slot(0..31: 8 channels each) + 32*rowgroup(0..7).
__global__ __launch_bounds__(256) void k_pool(const bf16* __restrict__ h,
                                              const bf16* __restrict__ conv,
                                              const float* __restrict__ ss,
                                              const int* __restrict__ batch,
                                              float* __restrict__ gs,
                                              float* __restrict__ cnt) {
    int tid = threadIdx.x;
    int slot = tid & 31, rg = tid >> 5;
    int c0 = slot * 8;
    float sc[8], sb[8];
#pragma unroll
    for (int j = 0; j < 8; ++j) { sc[j] = ss[c0 + j]; sb[j] = ss[HIDC + c0 + j]; }
    float acc[8];
#pragma unroll
    for (int j = 0; j < 8; ++j) acc[j] = 0.f;
    float ccnt = 0.f;
    int cur = -1;
    int nend = min(blockIdx.x * NPP + NPP, NNODES);
    for (int n = blockIdx.x * NPP + rg; n < nend; n += 8) {
        int b = batch[n];
        if (b != cur) {
            if (cur >= 0) {
#pragma unroll
                for (int j = 0; j < 8; ++j)
                    atomicAdd(&gs[(size_t)cur * HIDC + c0 + j], acc[j]);
                if (slot == 0) atomicAdd(&cnt[cur], ccnt);
#pragma unroll
                for (int j = 0; j < 8; ++j) acc[j] = 0.f;
                ccnt = 0.f;
            }
            cur = b;
        }
        uint4 hv = ((const uint4*)h)[(size_t)n * 32 + slot];
        uint4 cv = ((const uint4*)conv)[(size_t)n * 32 + slot];
        unsigned hw[4] = {hv.x, hv.y, hv.z, hv.w};
        unsigned cw[4] = {cv.x, cv.y, cv.z, cv.w};
#pragma unroll
        for (int q = 0; q < 4; ++q) {
            float2 hf = unpk(hw[q]);
            float2 cf = unpk(cw[q]);
            acc[2 * q]     += hf.x + fmaxf(cf.x * sc[2 * q] + sb[2 * q], 0.f);
            acc[2 * q + 1] += hf.y + fmaxf(cf.y * sc[2 * q + 1] + sb[2 * q + 1], 0.f);
        }
        ccnt += 1.f;
    }
    if (cur >= 0) {
#pragma unroll
        for (int j = 0; j < 8; ++j)
            atomicAdd(&gs[(size_t)cur * HIDC + c0 + j], acc[j]);
        if (slot == 0) atomicAdd(&cnt[cur], ccnt);
    }
}

// 9. head GEMM + fused input transform + fused BN stats.
template <int K, int C, int FUSE>
__global__ __launch_bounds__(256) void k_gemmstats(const float* __restrict__ in,
                                                   const float* __restrict__ cnt,
                                                   const float* __restrict__ ssin,
                                                   const float* __restrict__ W,
                                                   float* __restrict__ out,
                                                   float* __restrict__ sums) {
    constexpr int RG = 256 / C;
    constexpr int RPT = RPBH / RG;
    __shared__ float rs[RPBH][K + 1];
    __shared__ float fac[RPBH];
    __shared__ float red[2][C];
    int tid = threadIdx.x;
    int r0 = blockIdx.x * RPBH;
    if (FUSE == 0 && tid < RPBH) fac[tid] = 1.f / fmaxf(cnt[r0 + tid], 1.f);
    if (tid < C) { red[0][tid] = 0.f; red[1][tid] = 0.f; }
    __syncthreads();
    for (int i = tid; i < RPBH * K; i += 256) {
        int r = i / K, k = i - r * K;
        float v = in[(size_t)(r0 + r) * K + k];
        if (FUSE == 0) v *= fac[r];
        else v = fmaxf(v * ssin[k] + ssin[K + k], 0.f);
        rs[r][k] = v;
    }
    __syncthreads();
    int c = tid % C;
    int g = tid / C;
    float acc[RPT];
#pragma unroll
    for (int j = 0; j < RPT; ++j) acc[j] = 0.f;
    for (int k = 0; k < K; ++k) {
        float w = W[k * C + c];
#pragma unroll
        for (int j = 0; j < RPT; ++j) acc[j] += rs[g * RPT + j][k] * w;
    }
    float s = 0.f, s2 = 0.f;
#pragma unroll
    for (int j = 0; j < RPT; ++j) {
        int r = g * RPT + j;
        out[(size_t)(r0 + r) * C + c] = acc[j];
        s += acc[j];
        s2 += acc[j] * acc[j];
    }
    atomicAdd(&red[0][c], s);
    atomicAdd(&red[1][c], s2);
    __syncthreads();
    if (tid < C) {
        atomicAdd(&sums[tid], red[0][tid]);
        atomicAdd(&sums[C + tid], red[1][tid]);
    }
}

// 12. final linear with fused BN2+ReLU
__global__ __launch_bounds__(256) void k_final2(const float* __restrict__ r2,
                                                const float* __restrict__ ss,
                                                const float* __restrict__ w3,
                                                const float* __restrict__ b3,
                                                float* __restrict__ out) {
    int r = blockIdx.x * 256 + threadIdx.x;
    if (r >= NGR) return;
    float acc = 0.f;
#pragma unroll
    for (int k = 0; k < 64; ++k) {
        float v = fmaxf(r2[r * 64 + k] * ss[k] + ss[64 + k], 0.f);
        acc += v * w3[k];
    }
    out[r] = acc + b3[0];
}

static inline size_t alignup(size_t v) { return (v + 255) & ~(size_t)255; }

static size_t carve_need(int E) {
    size_t off = 0;
    off = alignup(off + (size_t)NNODES * HIDC * 2);            // h bf16
    off = alignup(off + (size_t)NNODES * BFD * 2);             // bases bf16
    off = alignup(off + (size_t)NNODES * NCOMB * 2);           // wco bf16
    off = alignup(off + (size_t)NNODES * HIDC * 2);            // conv bf16
    off = alignup(off + (size_t)(NNODES + 1) * 4);             // rowptr
    off = alignup(off + (size_t)NNODES * 4);                   // cursor
    off = alignup(off + (size_t)E * 4);                        // csr
    off = alignup(off + (size_t)E * 8);                        // ebuf (pool aliases)
    off = alignup(off + 2 * HIDC * 4);                         // sums
    off = alignup(off + 2 * HIDC * 4);                         // ss
    off = alignup(off + 256 * 4);                              // btot
    off = alignup(off + 256 * 4);                              // boff
    off = alignup(off + 256 * 4);                              // gcur
    off = alignup(off + (size_t)LAYERSN * PBL * 8 * 2);        // Bp4
    off = alignup(off + (size_t)AGGBLK * 512 * 4);             // partials
    return off;
}

static void run_all(const int* x, const int* esrc, const int* edst, const int* batch,
                    const float* emb, const float* basesW, const float* combW,
                    const float* combB, const float* convB, const float* bnG,
                    const float* bnB, const float* w1, const float* bn1g,
                    const float* bn1b, const float* w2, const float* bn2g,
                    const float* bn2b, const float* w3, const float* b3, int E,
                    float* out, char* base, hipStream_t stream) {
    size_t off = 0;
    bf16* h = (bf16*)(base + off);     off = alignup(off + (size_t)NNODES * HIDC * 2);
    bf16* bases = (bf16*)(base + off); off = alignup(off + (size_t)NNODES * BFD * 2);
    bf16* wco = (bf16*)(base + off);   off = alignup(off + (size_t)NNODES * NCOMB * 2);
    bf16* conv = (bf16*)(base + off);  off = alignup(off + (size_t)NNODES * HIDC * 2);
    int* rowptr = (int*)(base + off);  off = alignup(off + (size_t)(NNODES + 1) * 4);
    int* cursor = (int*)(base + off);  off = alignup(off + (size_t)NNODES * 4);
    int* csr = (int*)(base + off);     off = alignup(off + (size_t)E * 4);
    size_t o_ebuf = off;
    uint2* ebuf = (uint2*)(base + off); off = alignup(off + (size_t)E * 8);
    float* sums = (float*)(base + off); off = alignup(off + 2 * HIDC * 4);
    float* ss = (float*)(base + off);   off = alignup(off + 2 * HIDC * 4);
    int* btot = (int*)(base + off);     off = alignup(off + 256 * 4);
    int* boff = (int*)(base + off);     off = alignup(off + 256 * 4);
    int* gcur = (int*)(base + off);     off = alignup(off + 256 * 4);
    bf16* Bp4 = (bf16*)(base + off);    off = alignup(off + (size_t)LAYERSN * PBL * 8 * 2);
    float* partials = (float*)(base + off); off = alignup(off + (size_t)AGGBLK * 512 * 4);
    size_t po = o_ebuf;
    float* gs = (float*)(base + po);  po = alignup(po + (size_t)NGR * HIDC * 4);
    float* cnt = (float*)(base + po); po = alignup(po + (size_t)NGR * 4);
    float* r1 = (float*)(base + po);  po = alignup(po + (size_t)NGR * 128 * 4);
    float* r2 = (float*)(base + po);  po = alignup(po + (size_t)NGR * 64 * 4);

    const int NB = (NNODES + SCHUNK - 1) / SCHUNK;  // 98
    const int GEMMBLK = (NNODES + 63) / 64;         // 1563

    // once: CSR build (bucketed) + all-layer weight pack
    k_packB4<<<(LAYERSN * PBL + 255) / 256, 256, 0, stream>>>(basesW, combW, Bp4);
    hipMemsetAsync(cursor, 0, (size_t)NNODES * 4, stream);
    k_hist<<<(E + 255) / 256, 256, 0, stream>>>(edst, cursor, E);
    k_scansum<<<NB, 256, 0, stream>>>(cursor, btot, NNODES);
    k_scansmall<<<1, 64, 0, stream>>>(btot, boff, NB);
    k_scanapply<<<NB, 256, 0, stream>>>(cursor, boff, rowptr, cursor, NNODES);
    k_binit<<<1, NBUK, 0, stream>>>(rowptr, gcur);
    k_bucket<<<(E + 1023) / 1024, 256, 0, stream>>>(esrc, edst, gcur, ebuf, E);
    k_scatter2<<<NBUK * SC2K, 256, 0, stream>>>(ebuf, rowptr, cursor, csr);

    for (int l = 0; l < LAYERSN; ++l) {
        hipMemsetAsync(sums, 0, 2 * HIDC * 4, stream);
        if (l == 0) {
            k_gemm_mfma<0><<<GEMMBLK, 256, 32768 + 64 * NFEAT * 4, stream>>>(
                h, Bp4, combB, bases, wco, nullptr, ss, x, emb);
        } else {
            k_gemm_mfma<1><<<GEMMBLK, 256, 32768, stream>>>(
                h, Bp4 + (size_t)l * PBL * 8, combB + (size_t)l * NCOMB, bases, wco,
                conv, ss, nullptr, nullptr);
        }
        k_agg<bf16><<<AGGBLK, 256, 0, stream>>>(rowptr, csr, (const uint4*)bases,
                                                wco, convB + (size_t)l * HIDC, conv,
                                                partials);
        k_redstats<<<16, 256, 0, stream>>>(partials, sums);
        k_bnfin<HIDC><<<1, HIDC, 0, stream>>>(sums, bnG + (size_t)l * HIDC,
                                              bnB + (size_t)l * HIDC, (float)NNODES, ss);
    }

    hipMemsetAsync(gs, 0, (size_t)NGR * HIDC * 4, stream);
    hipMemsetAsync(cnt, 0, (size_t)NGR * 4, stream);
    k_pool<<<(NNODES + NPP - 1) / NPP, 256, 0, stream>>>(h, conv, ss, batch, gs, cnt);

    hipMemsetAsync(sums, 0, 2 * HIDC * 4, stream);
    k_gemmstats<256, 128, 0><<<NGR / RPBH, 256, 0, stream>>>(gs, cnt, nullptr, w1, r1, sums);
    k_bnfin<128><<<1, 128, 0, stream>>>(sums, bn1g, bn1b, (float)NGR, ss);
    hipMemsetAsync(sums, 0, 2 * HIDC * 4, stream);
    k_gemmstats<128, 64, 1><<<NGR / RPBH, 256, 0, stream>>>(r1, nullptr, ss, w2, r2, sums);
    k_bnfin<64><<<1, 64, 0, stream>>>(sums, bn2g, bn2b, (float)NGR, ss);
    k_final2<<<(NGR + 255) / 256, 256, 0, stream>>>(r2, ss, w3, b3, out);
}

extern "C" void kernel_launch(void* const* d_in, const int* in_sizes, int n_in,
                              void* d_out, int out_size, void* d_ws, size_t ws_size,
                              hipStream_t stream) {
    const int* x        = (const int*)d_in[0];
    const int* esrc     = (const int*)d_in[1];
    const int* edst     = (const int*)d_in[2];
    const int* batch    = (const int*)d_in[3];
    const float* emb    = (const float*)d_in[4];
    const float* basesW = (const float*)d_in[5];
    const float* combW  = (const float*)d_in[6];
    const float* combB  = (const float*)d_in[7];
    const float* convB  = (const float*)d_in[8];
    const float* bnG    = (const float*)d_in[9];
    const float* bnB    = (const float*)d_in[10];
    const float* w1     = (const float*)d_in[11];
    const float* bn1g   = (const float*)d_in[12];
    const float* bn1b   = (const float*)d_in[13];
    const float* w2     = (const float*)d_in[14];
    const float* bn2g   = (const float*)d_in[15];
    const float* bn2b   = (const float*)d_in[16];
    const float* w3     = (const float*)d_in[17];
    const float* b3     = (const float*)d_in[18];
    const int E = in_sizes[1];

    size_t need = carve_need(E);   // ~155 MB
    if (ws_size >= need) {
        run_all(x, esrc, edst, batch, emb, basesW, combW, combB, convB,
                bnG, bnB, w1, bn1g, bn1b, w2, bn2g, bn2b, w3, b3, E,
                (float*)d_out, (char*)d_ws, stream);
    } else {
        k_sentinel<<<(out_size + 255) / 256, 256, 0, stream>>>(
            (float*)d_out, out_size, (float)(ws_size >> 20));
    }
}

// Round 18
// 1232.505 us; speedup vs baseline: 1.4441x; 1.4441x over previous
//
#include <hip/hip_runtime.h>
#include <hip/hip_bf16.h>

#define NNODES 100000
#define HIDC 256
#define NFEAT 9
#define VOCABS 128
#define BFD 128        // bases output dim
#define NCOMB 96       // heads*bases*aggs
#define NGR 5000
#define LAYERSN 4
#define EPSV 1e-5f
#define SCHUNK 1024    // scan chunk
#define NPP 16         // rows per block in pooling
#define NTILES 14      // 224/16 output tiles (8 bases + 6 comb)
#define AGGBLK 2048    // agg grid
#define PBL (NTILES * 8 * 64)   // B fragments per layer
#define NBUK 32        // scatter buckets
#define BDIV 3125      // nodes per bucket
#define SC2K 64        // blocks per bucket in pass B
#define RPBH 20        // rows per block in head GEMM
#define OST 232        // LDS out-stage row stride (bf16), 16B-aligned rows

typedef __hip_bfloat16 bf16;
typedef __attribute__((ext_vector_type(8))) short sh8;
typedef __attribute__((ext_vector_type(4))) float fx4;

__device__ __forceinline__ float b2f(bf16 v) { return __bfloat162float(v); }
__device__ __forceinline__ bf16 f2b(float v) { return __float2bfloat16(v); }
__device__ __forceinline__ float ldf(const float* p) { return *p; }
__device__ __forceinline__ float ldf(const bf16* p) { return b2f(*p); }
__device__ __forceinline__ float2 unpk(unsigned u) {
    return make_float2(__uint_as_float(u << 16), __uint_as_float(u & 0xFFFF0000u));
}
__device__ __forceinline__ unsigned pack2bf(float a, float b) {
    unsigned ua = __float_as_uint(a), ub = __float_as_uint(b);
    ua = (ua + 0x7FFFu + ((ua >> 16) & 1u)) >> 16;
    ub = (ub + 0x7FFFu + ((ub >> 16) & 1u)) >> 16;
    return ua | (ub << 16);
}

// 0. sentinel
__global__ __launch_bounds__(256) void k_sentinel(float* out, int n, float val) {
    int i = blockIdx.x * 256 + threadIdx.x;
    if (i < n) out[i] = val;
}

// 2a. histogram of dst
__global__ __launch_bounds__(256) void k_hist(const int* __restrict__ dst,
                                              int* __restrict__ counts, int E) {
    int e = blockIdx.x * 256 + threadIdx.x;
    if (e < E) atomicAdd(&counts[dst[e]], 1);
}

__global__ __launch_bounds__(256) void k_scansum(const int* __restrict__ counts,
                                                 int* __restrict__ btot, int n) {
    __shared__ int sh[256];
    int b = blockIdx.x, t = threadIdx.x;
    int base = b * SCHUNK;
    int s = 0;
#pragma unroll
    for (int k = 0; k < 4; ++k) {
        int i = base + t + k * 256;
        if (i < n) s += counts[i];
    }
    sh[t] = s;
    __syncthreads();
    for (int st = 128; st > 0; st >>= 1) {
        if (t < st) sh[t] += sh[t + st];
        __syncthreads();
    }
    if (t == 0) btot[b] = sh[0];
}

__global__ void k_scansmall(const int* __restrict__ btot, int* __restrict__ boff, int nb) {
    if (threadIdx.x == 0 && blockIdx.x == 0) {
        int a = 0;
        for (int i = 0; i < nb; ++i) { boff[i] = a; a += btot[i]; }
    }
}

// 2b-3. per-chunk scan -> rowptr AND cursor
__global__ __launch_bounds__(256) void k_scanapply(const int* __restrict__ counts,
                                                   const int* __restrict__ boff,
                                                   int* __restrict__ rowptr,
                                                   int* __restrict__ cursor, int n) {
    __shared__ int sh[256];
    int b = blockIdx.x, t = threadIdx.x;
    int base = b * SCHUNK + t * 4;
    int c0 = (base + 0 < n) ? counts[base + 0] : 0;
    int c1 = (base + 1 < n) ? counts[base + 1] : 0;
    int c2 = (base + 2 < n) ? counts[base + 2] : 0;
    int c3 = (base + 3 < n) ? counts[base + 3] : 0;
    int s0 = c0, s1 = s0 + c1, s2 = s1 + c2, s3 = s2 + c3;
    sh[t] = s3;
    __syncthreads();
    for (int st = 1; st < 256; st <<= 1) {
        int v = (t >= st) ? sh[t - st] : 0;
        __syncthreads();
        sh[t] += v;
        __syncthreads();
    }
    int excl = sh[t] - s3 + boff[b];
    if (base + 0 < n) { rowptr[base + 1] = excl + s0; cursor[base + 0] = excl; }
    if (base + 1 < n) { rowptr[base + 2] = excl + s1; cursor[base + 1] = excl + s0; }
    if (base + 2 < n) { rowptr[base + 3] = excl + s2; cursor[base + 2] = excl + s1; }
    if (base + 3 < n) { rowptr[base + 4] = excl + s3; cursor[base + 3] = excl + s2; }
    if (b == 0 && t == 0) rowptr[0] = 0;
}

// 2e. bucket cursors
__global__ void k_binit(const int* __restrict__ rowptr, int* __restrict__ gcur) {
    int b = threadIdx.x;
    if (b < NBUK) gcur[b] = rowptr[b * BDIV];
}

// 2f. pass A: partition edges into ebuf by dst bucket
__global__ __launch_bounds__(256) void k_bucket(const int* __restrict__ src,
                                                const int* __restrict__ dst,
                                                int* __restrict__ gcur,
                                                uint2* __restrict__ ebuf, int E) {
    __shared__ int cnt[NBUK], base[NBUK], off[NBUK];
    int tid = threadIdx.x;
    if (tid < NBUK) { cnt[tid] = 0; off[tid] = 0; }
    __syncthreads();
    int d[4], s[4], bk[4];
    int e0 = blockIdx.x * 1024;
#pragma unroll
    for (int k = 0; k < 4; ++k) {
        int e = e0 + tid + k * 256;
        if (e < E) {
            d[k] = dst[e]; s[k] = src[e];
            bk[k] = d[k] / BDIV;
            atomicAdd(&cnt[bk[k]], 1);
        } else bk[k] = -1;
    }
    __syncthreads();
    if (tid < NBUK && cnt[tid] > 0) base[tid] = atomicAdd(&gcur[tid], cnt[tid]);
    __syncthreads();
#pragma unroll
    for (int k = 0; k < 4; ++k) {
        if (bk[k] >= 0) {
            int sl = base[bk[k]] + atomicAdd(&off[bk[k]], 1);
            ebuf[sl] = make_uint2((unsigned)d[k], (unsigned)s[k]);
        }
    }
}

// 2g. pass B: scatter within buckets
__global__ __launch_bounds__(256) void k_scatter2(const uint2* __restrict__ ebuf,
                                                  const int* __restrict__ rowptr,
                                                  int* __restrict__ cursor,
                                                  int* __restrict__ csr) {
    int bk = blockIdx.x & (NBUK - 1);
    int chunk = blockIdx.x >> 5;
    int lo = rowptr[bk * BDIV];
    int nhi = (bk + 1) * BDIV; if (nhi > NNODES) nhi = NNODES;
    int hi = rowptr[nhi];
    for (int e = lo + chunk * 256 + threadIdx.x; e < hi; e += SC2K * 256) {
        uint2 p = ebuf[e];
        int pos = atomicAdd(&cursor[p.x], 1);
        csr[pos] = (int)p.y;
    }
}

// 3a. pack W of ALL layers into MFMA B-fragment order
__global__ __launch_bounds__(256) void k_packB4(const float* __restrict__ basesW,
                                                const float* __restrict__ combW,
                                                bf16* __restrict__ Bp4) {
    int tid = blockIdx.x * 256 + threadIdx.x;
    if (tid >= LAYERSN * PBL) return;
    int layer = tid / PBL;
    int rem = tid % PBL;
    int l = rem & 63;
    int q = (rem >> 6) & 7;
    int t = rem >> 9;
    int n = t * 16 + (l & 15);
    int k0 = q * 32 + (l >> 4) * 8;
    const float* Wb = basesW + (size_t)layer * HIDC * BFD;
    const float* Wc = combW + (size_t)layer * HIDC * NCOMB;
    short out[8];
#pragma unroll
    for (int i = 0; i < 8; ++i) {
        int k = k0 + i;
        float v = (n < BFD) ? Wb[k * BFD + n] : Wc[k * NCOMB + (n - BFD)];
        unsigned u = __float_as_uint(v);
        out[i] = (short)((u + 0x7FFFu + ((u >> 16) & 1u)) >> 16);
    }
    *(sh8*)(Bp4 + (size_t)tid * 8) = *(sh8*)out;
}

// 3b. MFMA node GEMM (64 rows/block, 4 waves), dynamic LDS.
//     MODE 0: 35072 B (A-stage + xsh). MODE 1: 32768 B exactly -> 5 blocks/CU.
template <int MODE>
__global__ __launch_bounds__(256) void k_gemm_mfma(bf16* __restrict__ h,
                                                   const bf16* __restrict__ Bp,
                                                   const float* __restrict__ cb,
                                                   bf16* __restrict__ bases,
                                                   bf16* __restrict__ wco,
                                                   const bf16* __restrict__ convp,
                                                   const float* __restrict__ ss,
                                                   const int* __restrict__ x,
                                                   const float* __restrict__ emb) {
    extern __shared__ char smem[];
    unsigned* ldsA = (unsigned*)smem;                 // 32768 B
    int* xsh = (int*)(smem + 32768);                  // MODE 0 only: 2304 B
    int tid = threadIdx.x;
    size_t blk = blockIdx.x;
    if (MODE == 0) {
        for (int i = tid; i < 64 * NFEAT; i += 256) {
            int row = i / NFEAT;
            size_t rg = blk * 64 + row;
            xsh[i] = (rg < NNODES) ? x[rg * NFEAT + (i % NFEAT)] : 0;
        }
        __syncthreads();
    }
    // ---- stage h -> LDS (uint4 = 8 bf16 per thread per iter) ----
#pragma unroll
    for (int it = 0; it < 8; ++it) {
        int p = tid + it * 256;
        int row = p >> 5, g4 = p & 31;
        size_t rg = blk * 64 + row;
        uint4 word4 = make_uint4(0u, 0u, 0u, 0u);
        if (rg < NNODES) {
            int c0 = g4 * 8;
            unsigned res[4];
            if (MODE == 0) {
                float a[8];
#pragma unroll
                for (int q = 0; q < 8; ++q) a[q] = 0.f;
#pragma unroll
                for (int f = 0; f < NFEAT; ++f) {
                    const float* ep = emb + ((size_t)(f * VOCABS + xsh[row * NFEAT + f])) * HIDC + c0;
                    float4 e0 = *(const float4*)ep;
                    float4 e1 = *(const float4*)(ep + 4);
                    a[0] += e0.x; a[1] += e0.y; a[2] += e0.z; a[3] += e0.w;
                    a[4] += e1.x; a[5] += e1.y; a[6] += e1.z; a[7] += e1.w;
                }
#pragma unroll
                for (int q = 0; q < 4; ++q) res[q] = pack2bf(a[2 * q], a[2 * q + 1]);
            } else {
                uint4 hv = ((const uint4*)h)[rg * 32 + g4];
                uint4 cv = ((const uint4*)convp)[rg * 32 + g4];
                unsigned hw[4] = {hv.x, hv.y, hv.z, hv.w};
                unsigned cw[4] = {cv.x, cv.y, cv.z, cv.w};
#pragma unroll
                for (int q = 0; q < 4; ++q) {
                    float2 hf = unpk(hw[q]);
                    float2 cf = unpk(cw[q]);
                    float2 sc = *(const float2*)&ss[(g4 * 8) + 2 * q];
                    float2 sb = *(const float2*)&ss[HIDC + (g4 * 8) + 2 * q];
                    float a0 = hf.x + fmaxf(cf.x * sc.x + sb.x, 0.f);
                    float a1 = hf.y + fmaxf(cf.y * sc.y + sb.y, 0.f);
                    res[q] = pack2bf(a0, a1);
                }
            }
            word4 = make_uint4(res[0], res[1], res[2], res[3]);
            ((uint4*)h)[rg * 32 + g4] = word4;
        }
        ((uint4*)ldsA)[(row * 32 + g4) ^ (row & 7)] = word4;
    }
    __syncthreads();
    // ---- load A fragments ----
    int w = tid >> 6, l = tid & 63;
    int r = 16 * w + (l & 15);
    sh8 af[8];
    const char* lb = (const char*)ldsA;
#pragma unroll
    for (int q = 0; q < 8; ++q) {
        int byte = (r * 512 + q * 64 + (l >> 4) * 16) ^ ((r & 7) << 4);
        af[q] = *(const sh8*)(lb + byte);
    }
    __syncthreads();
    // ---- MFMA per tile + bf16 restage into LDS ----
    bf16* outl = (bf16*)smem;        // [64][OST] bf16, 29.7 KB
    const sh8* bp8 = (const sh8*)Bp;
#pragma unroll
    for (int t = 0; t < NTILES; ++t) {
        fx4 acc = (fx4){0.f, 0.f, 0.f, 0.f};
#pragma unroll
        for (int q = 0; q < 8; ++q) {
            acc = __builtin_amdgcn_mfma_f32_16x16x32_bf16(
                af[q], bp8[(t * 8 + q) * 64 + l], acc, 0, 0, 0);
        }
        int colb = t * 16 + (l & 15);
        float bias_v = (t >= 8) ? cb[colb - BFD] : 0.f;
#pragma unroll
        for (int j = 0; j < 4; ++j) {
            int rl = 16 * w + (l >> 4) * 4 + j;
            outl[rl * OST + colb] = f2b(acc[j] + bias_v);
        }
    }
    __syncthreads();
    // ---- coalesced global writes ----
    for (int i = tid; i < 64 * 16; i += 256) {
        int row = i >> 4, c4 = i & 15;
        size_t rg = blk * 64 + row;
        if (rg < NNODES)
            ((uint4*)bases)[rg * 16 + c4] = *(const uint4*)&outl[row * OST + c4 * 8];
    }
    for (int i = tid; i < 64 * 12; i += 256) {
        int row = i / 12, c4 = i % 12;
        size_t rg = blk * 64 + row;
        if (rg < NNODES)
            ((uint4*)wco)[rg * 12 + c4] = *(const uint4*)&outl[row * OST + BFD + c4 * 8];
    }
}

// 4. CSR aggregation + einsum + fused BN-stat partials. v6 + rowptr prefetch.
template <typename TW>
__global__ __launch_bounds__(256) void k_agg(const int* __restrict__ rowptr,
                                             const int* __restrict__ csr,
                                             const uint4* __restrict__ b4,
                                             const TW* __restrict__ wco,
                                             const float* __restrict__ bias,
                                             bf16* __restrict__ conv,
                                             float* __restrict__ partials) {
    __shared__ float agg[8][3][BFD];
    __shared__ float red[512];
    int tid = threadIdx.x;
    int g = tid >> 5, cl = tid & 31;
    int sub = cl >> 4;
    int ln16 = cl & 15;
    red[tid] = 0.f;
    red[tid + 256] = 0.f;
    __syncthreads();
    int hh = cl >> 2;
    int dbase = 8 * (cl & 3);
    float bb[8];
#pragma unroll
    for (int j = 0; j < 8; ++j) bb[j] = bias[8 * cl + j];
    float sts[8], sts2[8];
#pragma unroll
    for (int j = 0; j < 8; ++j) { sts[j] = 0.f; sts2[j] = 0.f; }
    int n0 = blockIdx.x * 8 + g;
    int pr0 = 0, pr1 = 0;
    if (n0 < NNODES) { pr0 = rowptr[n0]; pr1 = rowptr[n0 + 1]; }
    for (int n = n0; n < NNODES; n += AGGBLK * 8) {
        int r0 = pr0, r1 = pr1;
        int n2 = n + AGGBLK * 8;
        if (n2 < NNODES) { pr0 = rowptr[n2]; pr1 = rowptr[n2 + 1]; }
        float s0 = 0.f, s1 = 0.f, s2 = 0.f, s3 = 0.f;
        float s4 = 0.f, s5 = 0.f, s6 = 0.f, s7 = 0.f;
        float m0 = -INFINITY, m1 = -INFINITY, m2 = -INFINITY, m3 = -INFINITY;
        float m4 = -INFINITY, m5 = -INFINITY, m6 = -INFINITY, m7 = -INFINITY;
        int e = r0;
#define ACCU4(v) { float f0 = __uint_as_float((v).x << 16);            \
                   float f1 = __uint_as_float((v).x & 0xFFFF0000u);    \
                   float f2 = __uint_as_float((v).y << 16);            \
                   float f3 = __uint_as_float((v).y & 0xFFFF0000u);    \
                   float f4 = __uint_as_float((v).z << 16);            \
                   float f5 = __uint_as_float((v).z & 0xFFFF0000u);    \
                   float f6 = __uint_as_float((v).w << 16);            \
                   float f7 = __uint_as_float((v).w & 0xFFFF0000u);    \
                   s0 += f0; s1 += f1; s2 += f2; s3 += f3;             \
                   s4 += f4; s5 += f5; s6 += f6; s7 += f7;             \
                   m0 = fmaxf(m0, f0); m1 = fmaxf(m1, f1);             \
                   m2 = fmaxf(m2, f2); m3 = fmaxf(m3, f3);             \
                   m4 = fmaxf(m4, f4); m5 = fmaxf(m5, f5);             \
                   m6 = fmaxf(m6, f6); m7 = fmaxf(m7, f7); }
        for (; e + 8 <= r1; e += 8) {
            int i0 = csr[e + 0 + sub], i1 = csr[e + 2 + sub];
            int i2 = csr[e + 4 + sub], i3 = csr[e + 6 + sub];
            uint4 v0 = b4[(size_t)i0 * 16 + ln16];
            uint4 v1 = b4[(size_t)i1 * 16 + ln16];
            uint4 v2 = b4[(size_t)i2 * 16 + ln16];
            uint4 v3 = b4[(size_t)i3 * 16 + ln16];
            ACCU4(v0) ACCU4(v1) ACCU4(v2) ACCU4(v3)
        }
        for (; e + 2 <= r1; e += 2) {
            uint4 v = b4[(size_t)csr[e + sub] * 16 + ln16];
            ACCU4(v)
        }
        if (e < r1 && sub == 0) {
            uint4 v = b4[(size_t)csr[e] * 16 + ln16];
            ACCU4(v)
        }
#undef ACCU4
        s0 += __shfl_xor(s0, 16); s1 += __shfl_xor(s1, 16);
        s2 += __shfl_xor(s2, 16); s3 += __shfl_xor(s3, 16);
        s4 += __shfl_xor(s4, 16); s5 += __shfl_xor(s5, 16);
        s6 += __shfl_xor(s6, 16); s7 += __shfl_xor(s7, 16);
        m0 = fmaxf(m0, __shfl_xor(m0, 16)); m1 = fmaxf(m1, __shfl_xor(m1, 16));
        m2 = fmaxf(m2, __shfl_xor(m2, 16)); m3 = fmaxf(m3, __shfl_xor(m3, 16));
        m4 = fmaxf(m4, __shfl_xor(m4, 16)); m5 = fmaxf(m5, __shfl_xor(m5, 16));
        m6 = fmaxf(m6, __shfl_xor(m6, 16)); m7 = fmaxf(m7, __shfl_xor(m7, 16));
        if (sub == 0) {
            float inv = 1.0f / (float)(r1 - r0);
            int cb2 = ln16 * 8;
            *(float4*)&agg[g][0][cb2]     = make_float4(s0, s1, s2, s3);
            *(float4*)&agg[g][0][cb2 + 4] = make_float4(s4, s5, s6, s7);
            *(float4*)&agg[g][1][cb2]     = make_float4(s0 * inv, s1 * inv, s2 * inv, s3 * inv);
            *(float4*)&agg[g][1][cb2 + 4] = make_float4(s4 * inv, s5 * inv, s6 * inv, s7 * inv);
            *(float4*)&agg[g][2][cb2]     = make_float4(m0, m1, m2, m3);
            *(float4*)&agg[g][2][cb2 + 4] = make_float4(m4, m5, m6, m7);
        }
        const TW* wp = &wco[(size_t)n * NCOMB + hh * 12];
        float wv[12];
#pragma unroll
        for (int k = 0; k < 12; ++k) wv[k] = ldf(&wp[k]);
        float o[8];
#pragma unroll
        for (int j = 0; j < 8; ++j) {
            int d = dbase + j;
            float a = 0.f;
#pragma unroll
            for (int b = 0; b < 4; ++b) {
                a += wv[b] * agg[g][0][b * 32 + d];
                a += wv[4 + b] * agg[g][1][b * 32 + d];
                a += wv[8 + b] * agg[g][2][b * 32 + d];
            }
            a += bb[j];
            o[j] = a;
            sts[j] += a;
            sts2[j] += a * a;
        }
        uint4 cv = make_uint4(pack2bf(o[0], o[1]), pack2bf(o[2], o[3]),
                              pack2bf(o[4], o[5]), pack2bf(o[6], o[7]));
        ((uint4*)conv)[(size_t)n * 32 + cl] = cv;
    }
#pragma unroll
    for (int j = 0; j < 8; ++j) {
        atomicAdd(&red[8 * cl + j], sts[j]);
        atomicAdd(&red[256 + 8 * cl + j], sts2[j]);
    }
    __syncthreads();
    partials[(size_t)blockIdx.x * 512 + tid] = red[tid];
    partials[(size_t)blockIdx.x * 512 + 256 + tid] = red[tid + 256];
}

// 4b. reduce partials -> sums[512]
__global__ __launch_bounds__(256) void k_redstats(const float* __restrict__ partials,
                                                  float* __restrict__ sums) {
    int g = blockIdx.x * 256 + threadIdx.x;
    int j = g & 511;
    int chunk = g >> 9;
    float s = 0.f;
    for (int pb = chunk * 256; pb < (chunk + 1) * 256; ++pb)
        s += partials[(size_t)pb * 512 + j];
    atomicAdd(&sums[j], s);
}

// 6. BN finalize
template <int C>
__global__ void k_bnfin(const float* __restrict__ sums, const float* __restrict__ g,
                        const float* __restrict__ b, float nrows, float* __restrict__ ss) {
    int c = threadIdx.x;
    float mu = sums[c] / nrows;
    float var = sums[C + c] / nrows - mu * mu;
    float rstd = rsqrtf(fmaxf(var, 0.f) + EPSV);
    float sc = rstd * g[c];
    ss[c] = sc;
    ss[C + c] = b[c] - mu * sc;
}

// 8. pooling with FUSED final-layer BN-apply+ReLU+residual (round-16 form:
//    1 thread = 1 channel over 16 consecutive rows -> ~1-2 boundary flushes).
__global__ __launch_bounds__(256) void k_pool(const bf16* __restrict__ h,
                                              const bf16* __restrict__ conv,
                                              const float* __restrict__ ss,
                                              const int* __restrict__ batch,
                                              float* __restrict__ gs,
                                              float* __restrict__ cnt) {
    int c = threadIdx.x;
    float sc = ss[c], sb = ss[HIDC + c];
    int n0 = blockIdx.x * NPP;
    int end = min(n0 + NPP, NNODES);
    float acc = 0.f, ccnt = 0.f;
    int cur = batch[n0];
    for (int n = n0; n < end; ++n) {
        int b = batch[n];
        if (b != cur) {
            atomicAdd(&gs[(size_t)cur * HIDC + c], acc);
            if (c == 0) atomicAdd(&cnt[cur], ccnt);
            acc = 0.f; ccnt = 0.f; cur = b;
        }
        float v = b2f(conv[(size_t)n * HIDC + c]) * sc + sb;
        acc += b2f(h[(size_t)n * HIDC + c]) + fmaxf(v, 0.f);
        ccnt += 1.f;
    }
    atomicAdd(&gs[(size_t)cur * HIDC + c], acc);
    if (c == 0) atomicAdd(&cnt[cur], ccnt);
}

// 9. head GEMM + fused input transform + fused BN stats.
template <int K, int C, int FUSE>
__global__ __launch_bounds__(256) void k_gemmstats(const float* __restrict__ in,
                                                   const float* __restrict__ cnt,
                                                   const float* __restrict__ ssin,
                                                   const float* __restrict__ W,
                                                   float* __restrict__ out,
                                                   float* __restrict__ sums) {
    constexpr int RG = 256 / C;
    constexpr int RPT = RPBH / RG;
    __shared__ float rs[RPBH][K + 1];
    __shared__ float fac[RPBH];
    __shared__ float red[2][C];
    int tid = threadIdx.x;
    int r0 = blockIdx.x * RPBH;
    if (FUSE == 0 && tid < RPBH) fac[tid] = 1.f / fmaxf(cnt[r0 + tid], 1.f);
    if (tid < C) { red[0][tid] = 0.f; red[1][tid] = 0.f; }
    __syncthreads();
    for (int i = tid; i < RPBH * K; i += 256) {
        int r = i / K, k = i - r * K;
        float v = in[(size_t)(r0 + r) * K + k];
        if (FUSE == 0) v *= fac[r];
        else v = fmaxf(v * ssin[k] + ssin[K + k], 0.f);
        rs[r][k] = v;
    }
    __syncthreads();
    int c = tid % C;
    int g = tid / C;
    float acc[RPT];
#pragma unroll
    for (int j = 0; j < RPT; ++j) acc[j] = 0.f;
    for (int k = 0; k < K; ++k) {
        float w = W[k * C + c];
#pragma unroll
        for (int j = 0; j < RPT; ++j) acc[j] += rs[g * RPT + j][k] * w;
    }
    float s = 0.f, s2 = 0.f;
#pragma unroll
    for (int j = 0; j < RPT; ++j) {
        int r = g * RPT + j;
        out[(size_t)(r0 + r) * C + c] = acc[j];
        s += acc[j];
        s2 += acc[j] * acc[j];
    }
    atomicAdd(&red[0][c], s);
    atomicAdd(&red[1][c], s2);
    __syncthreads();
    if (tid < C) {
        atomicAdd(&sums[tid], red[0][tid]);
        atomicAdd(&sums[C + tid], red[1][tid]);
    }
}

// 12. final linear with fused BN2+ReLU
__global__ __launch_bounds__(256) void k_final2(const float* __restrict__ r2,
                                                const float* __restrict__ ss,
                                                const float* __restrict__ w3,
                                                const float* __restrict__ b3,
                                                float* __restrict__ out) {
    int r = blockIdx.x * 256 + threadIdx.x;
    if (r >= NGR) return;
    float acc = 0.f;
#pragma unroll
    for (int k = 0; k < 64; ++k) {
        float v = fmaxf(r2[r * 64 + k] * ss[k] + ss[64 + k], 0.f);
        acc += v * w3[k];
    }
    out[r] = acc + b3[0];
}

static inline size_t alignup(size_t v) { return (v + 255) & ~(size_t)255; }

static size_t carve_need(int E) {
    size_t off = 0;
    off = alignup(off + (size_t)NNODES * HIDC * 2);            // h bf16
    off = alignup(off + (size_t)NNODES * BFD * 2);             // bases bf16
    off = alignup(off + (size_t)NNODES * NCOMB * 2);           // wco bf16
    off = alignup(off + (size_t)NNODES * HIDC * 2);            // conv bf16
    off = alignup(off + (size_t)(NNODES + 1) * 4);             // rowptr
    off = alignup(off + (size_t)NNODES * 4);                   // cursor
    off = alignup(off + (size_t)E * 4);                        // csr
    off = alignup(off + (size_t)E * 8);                        // ebuf (pool aliases)
    off = alignup(off + 2 * HIDC * 4);                         // sums
    off = alignup(off + 2 * HIDC * 4);                         // ss
    off = alignup(off + 256 * 4);                              // btot
    off = alignup(off + 256 * 4);                              // boff
    off = alignup(off + 256 * 4);                              // gcur
    off = alignup(off + (size_t)LAYERSN * PBL * 8 * 2);        // Bp4
    off = alignup(off + (size_t)AGGBLK * 512 * 4);             // partials
    return off;
}

static void run_all(const int* x, const int* esrc, const int* edst, const int* batch,
                    const float* emb, const float* basesW, const float* combW,
                    const float* combB, const float* convB, const float* bnG,
                    const float* bnB, const float* w1, const float* bn1g,
                    const float* bn1b, const float* w2, const float* bn2g,
                    const float* bn2b, const float* w3, const float* b3, int E,
                    float* out, char* base, hipStream_t stream) {
    size_t off = 0;
    bf16* h = (bf16*)(base + off);     off = alignup(off + (size_t)NNODES * HIDC * 2);
    bf16* bases = (bf16*)(base + off); off = alignup(off + (size_t)NNODES * BFD * 2);
    bf16* wco = (bf16*)(base + off);   off = alignup(off + (size_t)NNODES * NCOMB * 2);
    bf16* conv = (bf16*)(base + off);  off = alignup(off + (size_t)NNODES * HIDC * 2);
    int* rowptr = (int*)(base + off);  off = alignup(off + (size_t)(NNODES + 1) * 4);
    int* cursor = (int*)(base + off);  off = alignup(off + (size_t)NNODES * 4);
    int* csr = (int*)(base + off);     off = alignup(off + (size_t)E * 4);
    size_t o_ebuf = off;
    uint2* ebuf = (uint2*)(base + off); off = alignup(off + (size_t)E * 8);
    float* sums = (float*)(base + off); off = alignup(off + 2 * HIDC * 4);
    float* ss = (float*)(base + off);   off = alignup(off + 2 * HIDC * 4);
    int* btot = (int*)(base + off);     off = alignup(off + 256 * 4);
    int* boff = (int*)(base + off);     off = alignup(off + 256 * 4);
    int* gcur = (int*)(base + off);     off = alignup(off + 256 * 4);
    bf16* Bp4 = (bf16*)(base + off);    off = alignup(off + (size_t)LAYERSN * PBL * 8 * 2);
    float* partials = (float*)(base + off); off = alignup(off + (size_t)AGGBLK * 512 * 4);
    size_t po = o_ebuf;
    float* gs = (float*)(base + po);  po = alignup(po + (size_t)NGR * HIDC * 4);
    float* cnt = (float*)(base + po); po = alignup(po + (size_t)NGR * 4);
    float* r1 = (float*)(base + po);  po = alignup(po + (size_t)NGR * 128 * 4);
    float* r2 = (float*)(base + po);  po = alignup(po + (size_t)NGR * 64 * 4);

    const int NB = (NNODES + SCHUNK - 1) / SCHUNK;  // 98
    const int GEMMBLK = (NNODES + 63) / 64;         // 1563

    // once: CSR build (bucketed) + all-layer weight pack
    k_packB4<<<(LAYERSN * PBL + 255) / 256, 256, 0, stream>>>(basesW, combW, Bp4);
    hipMemsetAsync(cursor, 0, (size_t)NNODES * 4, stream);
    k_hist<<<(E + 255) / 256, 256, 0, stream>>>(edst, cursor, E);
    k_scansum<<<NB, 256, 0, stream>>>(cursor, btot, NNODES);
    k_scansmall<<<1, 64, 0, stream>>>(btot, boff, NB);
    k_scanapply<<<NB, 256, 0, stream>>>(cursor, boff, rowptr, cursor, NNODES);
    k_binit<<<1, NBUK, 0, stream>>>(rowptr, gcur);
    k_bucket<<<(E + 1023) / 1024, 256, 0, stream>>>(esrc, edst, gcur, ebuf, E);
    k_scatter2<<<NBUK * SC2K, 256, 0, stream>>>(ebuf, rowptr, cursor, csr);

    for (int l = 0; l < LAYERSN; ++l) {
        hipMemsetAsync(sums, 0, 2 * HIDC * 4, stream);
        if (l == 0) {
            k_gemm_mfma<0><<<GEMMBLK, 256, 32768 + 64 * NFEAT * 4, stream>>>(
                h, Bp4, combB, bases, wco, nullptr, ss, x, emb);
        } else {
            k_gemm_mfma<1><<<GEMMBLK, 256, 32768, stream>>>(
                h, Bp4 + (size_t)l * PBL * 8, combB + (size_t)l * NCOMB, bases, wco,
                conv, ss, nullptr, nullptr);
        }
        k_agg<bf16><<<AGGBLK, 256, 0, stream>>>(rowptr, csr, (const uint4*)bases,
                                                wco, convB + (size_t)l * HIDC, conv,
                                                partials);
        k_redstats<<<16, 256, 0, stream>>>(partials, sums);
        k_bnfin<HIDC><<<1, HIDC, 0, stream>>>(sums, bnG + (size_t)l * HIDC,
                                              bnB + (size_t)l * HIDC, (float)NNODES, ss);
    }

    hipMemsetAsync(gs, 0, (size_t)NGR * HIDC * 4, stream);
    hipMemsetAsync(cnt, 0, (size_t)NGR * 4, stream);
    k_pool<<<(NNODES + NPP - 1) / NPP, 256, 0, stream>>>(h, conv, ss, batch, gs, cnt);

    hipMemsetAsync(sums, 0, 2 * HIDC * 4, stream);
    k_gemmstats<256, 128, 0><<<NGR / RPBH, 256, 0, stream>>>(gs, cnt, nullptr, w1, r1, sums);
    k_bnfin<128><<<1, 128, 0, stream>>>(sums, bn1g, bn1b, (float)NGR, ss);
    hipMemsetAsync(sums, 0, 2 * HIDC * 4, stream);
    k_gemmstats<128, 64, 1><<<NGR / RPBH, 256, 0, stream>>>(r1, nullptr, ss, w2, r2, sums);
    k_bnfin<64><<<1, 64, 0, stream>>>(sums, bn2g, bn2b, (float)NGR, ss);
    k_final2<<<(NGR + 255) / 256, 256, 0, stream>>>(r2, ss, w3, b3, out);
}

extern "C" void kernel_launch(void* const* d_in, const int* in_sizes, int n_in,
                              void* d_out, int out_size, void* d_ws, size_t ws_size,
                              hipStream_t stream) {
    const int* x        = (const int*)d_in[0];
    const int* esrc     = (const int*)d_in[1];
    const int* edst     = (const int*)d_in[2];
    const int* batch    = (const int*)d_in[3];
    const float* emb    = (const float*)d_in[4];
    const float* basesW = (const float*)d_in[5];
    const float* combW  = (const float*)d_in[6];
    const float* combB  = (const float*)d_in[7];
    const float* convB  = (const float*)d_in[8];
    const float* bnG    = (const float*)d_in[9];
    const float* bnB    = (const float*)d_in[10];
    const float* w1     = (const float*)d_in[11];
    const float* bn1g   = (const float*)d_in[12];
    const float* bn1b   = (const float*)d_in[13];
    const float* w2     = (const float*)d_in[14];
    const float* bn2g   = (const float*)d_in[15];
    const float* bn2b   = (const float*)d_in[16];
    const float* w3     = (const float*)d_in[17];
    const float* b3     = (const float*)d_in[18];
    const int E = in_sizes[1];

    size_t need = carve_need(E);   // ~155 MB
    if (ws_size >= need) {
        run_all(x, esrc, edst, batch, emb, basesW, combW, combB, convB,
                bnG, bnB, w1, bn1g, bn1b, w2, bn2g, bn2b, w3, b3, E,
                (float*)d_out, (char*)d_ws, stream);
    } else {
        k_sentinel<<<(out_size + 255) / 256, 256, 0, stream>>>(
            (float*)d_out, out_size, (float)(ws_size >> 20));
    }
}

// Round 19
// 1203.026 us; speedup vs baseline: 1.4795x; 1.0245x over previous
//
#include <hip/hip_runtime.h>
#include <hip/hip_bf16.h>

#define NNODES 100000
#define HIDC 256
#define NFEAT 9
#define VOCABS 128
#define BFD 128        // bases output dim
#define NCOMB 96       // heads*bases*aggs
#define NGR 5000
#define LAYERSN 4
#define EPSV 1e-5f
#define SCHUNK 1024    // scan chunk
#define NPP 16         // rows per block in pooling
#define NTILES 14      // 224/16 output tiles (8 bases + 6 comb)
#define AGGBLK 2048    // agg grid
#define PBL (NTILES * 8 * 64)   // B fragments per layer
#define NBUK 32        // scatter buckets
#define BDIV 3125      // nodes per bucket
#define SC2K 64        // blocks per bucket in pass B
#define RPBH 20        // rows per block in head GEMM
#define OST 232        // LDS out-stage row stride (bf16), 16B-aligned rows

typedef __hip_bfloat16 bf16;
typedef __attribute__((ext_vector_type(8))) short sh8;
typedef __attribute__((ext_vector_type(4))) float fx4;

__device__ __forceinline__ float b2f(bf16 v) { return __bfloat162float(v); }
__device__ __forceinline__ bf16 f2b(float v) { return __float2bfloat16(v); }
__device__ __forceinline__ float ldf(const float* p) { return *p; }
__device__ __forceinline__ float ldf(const bf16* p) { return b2f(*p); }
__device__ __forceinline__ float2 unpk(unsigned u) {
    return make_float2(__uint_as_float(u << 16), __uint_as_float(u & 0xFFFF0000u));
}
__device__ __forceinline__ unsigned pack2bf(float a, float b) {
    unsigned ua = __float_as_uint(a), ub = __float_as_uint(b);
    ua = (ua + 0x7FFFu + ((ua >> 16) & 1u)) >> 16;
    ub = (ub + 0x7FFFu + ((ub >> 16) & 1u)) >> 16;
    return ua | (ub << 16);
}

// 0. sentinel
__global__ __launch_bounds__(256) void k_sentinel(float* out, int n, float val) {
    int i = blockIdx.x * 256 + threadIdx.x;
    if (i < n) out[i] = val;
}

// 2a. histogram of dst
__global__ __launch_bounds__(256) void k_hist(const int* __restrict__ dst,
                                              int* __restrict__ counts, int E) {
    int e = blockIdx.x * 256 + threadIdx.x;
    if (e < E) atomicAdd(&counts[dst[e]], 1);
}

__global__ __launch_bounds__(256) void k_scansum(const int* __restrict__ counts,
                                                 int* __restrict__ btot, int n) {
    __shared__ int sh[256];
    int b = blockIdx.x, t = threadIdx.x;
    int base = b * SCHUNK;
    int s = 0;
#pragma unroll
    for (int k = 0; k < 4; ++k) {
        int i = base + t + k * 256;
        if (i < n) s += counts[i];
    }
    sh[t] = s;
    __syncthreads();
    for (int st = 128; st > 0; st >>= 1) {
        if (t < st) sh[t] += sh[t + st];
        __syncthreads();
    }
    if (t == 0) btot[b] = sh[0];
}

__global__ void k_scansmall(const int* __restrict__ btot, int* __restrict__ boff, int nb) {
    if (threadIdx.x == 0 && blockIdx.x == 0) {
        int a = 0;
        for (int i = 0; i < nb; ++i) { boff[i] = a; a += btot[i]; }
    }
}

// 2b-3. per-chunk scan -> rowptr AND cursor
__global__ __launch_bounds__(256) void k_scanapply(const int* __restrict__ counts,
                                                   const int* __restrict__ boff,
                                                   int* __restrict__ rowptr,
                                                   int* __restrict__ cursor, int n) {
    __shared__ int sh[256];
    int b = blockIdx.x, t = threadIdx.x;
    int base = b * SCHUNK + t * 4;
    int c0 = (base + 0 < n) ? counts[base + 0] : 0;
    int c1 = (base + 1 < n) ? counts[base + 1] : 0;
    int c2 = (base + 2 < n) ? counts[base + 2] : 0;
    int c3 = (base + 3 < n) ? counts[base + 3] : 0;
    int s0 = c0, s1 = s0 + c1, s2 = s1 + c2, s3 = s2 + c3;
    sh[t] = s3;
    __syncthreads();
    for (int st = 1; st < 256; st <<= 1) {
        int v = (t >= st) ? sh[t - st] : 0;
        __syncthreads();
        sh[t] += v;
        __syncthreads();
    }
    int excl = sh[t] - s3 + boff[b];
    if (base + 0 < n) { rowptr[base + 1] = excl + s0; cursor[base + 0] = excl; }
    if (base + 1 < n) { rowptr[base + 2] = excl + s1; cursor[base + 1] = excl + s0; }
    if (base + 2 < n) { rowptr[base + 3] = excl + s2; cursor[base + 2] = excl + s1; }
    if (base + 3 < n) { rowptr[base + 4] = excl + s3; cursor[base + 3] = excl + s2; }
    if (b == 0 && t == 0) rowptr[0] = 0;
}

// 2e. bucket cursors
__global__ void k_binit(const int* __restrict__ rowptr, int* __restrict__ gcur) {
    int b = threadIdx.x;
    if (b < NBUK) gcur[b] = rowptr[b * BDIV];
}

// 2f. pass A: partition edges into ebuf by dst bucket
__global__ __launch_bounds__(256) void k_bucket(const int* __restrict__ src,
                                                const int* __restrict__ dst,
                                                int* __restrict__ gcur,
                                                uint2* __restrict__ ebuf, int E) {
    __shared__ int cnt[NBUK], base[NBUK], off[NBUK];
    int tid = threadIdx.x;
    if (tid < NBUK) { cnt[tid] = 0; off[tid] = 0; }
    __syncthreads();
    int d[4], s[4], bk[4];
    int e0 = blockIdx.x * 1024;
#pragma unroll
    for (int k = 0; k < 4; ++k) {
        int e = e0 + tid + k * 256;
        if (e < E) {
            d[k] = dst[e]; s[k] = src[e];
            bk[k] = d[k] / BDIV;
            atomicAdd(&cnt[bk[k]], 1);
        } else bk[k] = -1;
    }
    __syncthreads();
    if (tid < NBUK && cnt[tid] > 0) base[tid] = atomicAdd(&gcur[tid], cnt[tid]);
    __syncthreads();
#pragma unroll
    for (int k = 0; k < 4; ++k) {
        if (bk[k] >= 0) {
            int sl = base[bk[k]] + atomicAdd(&off[bk[k]], 1);
            ebuf[sl] = make_uint2((unsigned)d[k], (unsigned)s[k]);
        }
    }
}

// 2g. pass B: scatter within buckets
__global__ __launch_bounds__(256) void k_scatter2(const uint2* __restrict__ ebuf,
                                                  const int* __restrict__ rowptr,
                                                  int* __restrict__ cursor,
                                                  int* __restrict__ csr) {
    int bk = blockIdx.x & (NBUK - 1);
    int chunk = blockIdx.x >> 5;
    int lo = rowptr[bk * BDIV];
    int nhi = (bk + 1) * BDIV; if (nhi > NNODES) nhi = NNODES;
    int hi = rowptr[nhi];
    for (int e = lo + chunk * 256 + threadIdx.x; e < hi; e += SC2K * 256) {
        uint2 p = ebuf[e];
        int pos = atomicAdd(&cursor[p.x], 1);
        csr[pos] = (int)p.y;
    }
}

// 3a. pack W of ALL layers into MFMA B-fragment order
__global__ __launch_bounds__(256) void k_packB4(const float* __restrict__ basesW,
                                                const float* __restrict__ combW,
                                                bf16* __restrict__ Bp4) {
    int tid = blockIdx.x * 256 + threadIdx.x;
    if (tid >= LAYERSN * PBL) return;
    int layer = tid / PBL;
    int rem = tid % PBL;
    int l = rem & 63;
    int q = (rem >> 6) & 7;
    int t = rem >> 9;
    int n = t * 16 + (l & 15);
    int k0 = q * 32 + (l >> 4) * 8;
    const float* Wb = basesW + (size_t)layer * HIDC * BFD;
    const float* Wc = combW + (size_t)layer * HIDC * NCOMB;
    short out[8];
#pragma unroll
    for (int i = 0; i < 8; ++i) {
        int k = k0 + i;
        float v = (n < BFD) ? Wb[k * BFD + n] : Wc[k * NCOMB + (n - BFD)];
        unsigned u = __float_as_uint(v);
        out[i] = (short)((u + 0x7FFFu + ((u >> 16) & 1u)) >> 16);
    }
    *(sh8*)(Bp4 + (size_t)tid * 8) = *(sh8*)out;
}

// 3b. MFMA node GEMM (64 rows/block, 4 waves), STATIC LDS (round-16 form —
//     the measured-best variant; dynamic-LDS trial was neutral-to-worse).
template <int MODE>
__global__ __launch_bounds__(256) void k_gemm_mfma(bf16* __restrict__ h,
                                                   const bf16* __restrict__ Bp,
                                                   const float* __restrict__ cb,
                                                   bf16* __restrict__ bases,
                                                   bf16* __restrict__ wco,
                                                   const bf16* __restrict__ convp,
                                                   const float* __restrict__ ss,
                                                   const int* __restrict__ x,
                                                   const float* __restrict__ emb) {
    __shared__ unsigned ldsA[8192];   // 32 KB: A-stage, then C-stage (bf16[64][OST])
    __shared__ int xsh[64 * NFEAT];
    int tid = threadIdx.x;
    size_t blk = blockIdx.x;
    if (MODE == 0) {
        for (int i = tid; i < 64 * NFEAT; i += 256) {
            int row = i / NFEAT;
            size_t rg = blk * 64 + row;
            xsh[i] = (rg < NNODES) ? x[rg * NFEAT + (i % NFEAT)] : 0;
        }
        __syncthreads();
    }
    // ---- stage h -> LDS (uint4 = 8 bf16 per thread per iter) ----
#pragma unroll
    for (int it = 0; it < 8; ++it) {
        int p = tid + it * 256;
        int row = p >> 5, g4 = p & 31;
        size_t rg = blk * 64 + row;
        uint4 word4 = make_uint4(0u, 0u, 0u, 0u);
        if (rg < NNODES) {
            int c0 = g4 * 8;
            unsigned res[4];
            if (MODE == 0) {
                float a[8];
#pragma unroll
                for (int q = 0; q < 8; ++q) a[q] = 0.f;
#pragma unroll
                for (int f = 0; f < NFEAT; ++f) {
                    const float* ep = emb + ((size_t)(f * VOCABS + xsh[row * NFEAT + f])) * HIDC + c0;
                    float4 e0 = *(const float4*)ep;
                    float4 e1 = *(const float4*)(ep + 4);
                    a[0] += e0.x; a[1] += e0.y; a[2] += e0.z; a[3] += e0.w;
                    a[4] += e1.x; a[5] += e1.y; a[6] += e1.z; a[7] += e1.w;
                }
#pragma unroll
                for (int q = 0; q < 4; ++q) res[q] = pack2bf(a[2 * q], a[2 * q + 1]);
            } else {
                uint4 hv = ((const uint4*)h)[rg * 32 + g4];
                uint4 cv = ((const uint4*)convp)[rg * 32 + g4];
                unsigned hw[4] = {hv.x, hv.y, hv.z, hv.w};
                unsigned cw[4] = {cv.x, cv.y, cv.z, cv.w};
#pragma unroll
                for (int q = 0; q < 4; ++q) {
                    float2 hf = unpk(hw[q]);
                    float2 cf = unpk(cw[q]);
                    float2 sc = *(const float2*)&ss[c0 + 2 * q];
                    float2 sb = *(const float2*)&ss[HIDC + c0 + 2 * q];
                    float a0 = hf.x + fmaxf(cf.x * sc.x + sb.x, 0.f);
                    float a1 = hf.y + fmaxf(cf.y * sc.y + sb.y, 0.f);
                    res[q] = pack2bf(a0, a1);
                }
            }
            word4 = make_uint4(res[0], res[1], res[2], res[3]);
            ((uint4*)h)[rg * 32 + g4] = word4;
        }
        ((uint4*)ldsA)[(row * 32 + g4) ^ (row & 7)] = word4;
    }
    __syncthreads();
    // ---- load A fragments ----
    int w = tid >> 6, l = tid & 63;
    int r = 16 * w + (l & 15);
    sh8 af[8];
    const char* lb = (const char*)ldsA;
#pragma unroll
    for (int q = 0; q < 8; ++q) {
        int byte = (r * 512 + q * 64 + (l >> 4) * 16) ^ ((r & 7) << 4);
        af[q] = *(const sh8*)(lb + byte);
    }
    __syncthreads();
    // ---- MFMA per tile + bf16 restage into LDS ----
    bf16* outl = (bf16*)ldsA;        // [64][OST] bf16, 29.7 KB
    const sh8* bp8 = (const sh8*)Bp;
#pragma unroll
    for (int t = 0; t < NTILES; ++t) {
        fx4 acc = (fx4){0.f, 0.f, 0.f, 0.f};
#pragma unroll
        for (int q = 0; q < 8; ++q) {
            acc = __builtin_amdgcn_mfma_f32_16x16x32_bf16(
                af[q], bp8[(t * 8 + q) * 64 + l], acc, 0, 0, 0);
        }
        int colb = t * 16 + (l & 15);
        float bias_v = (t >= 8) ? cb[colb - BFD] : 0.f;
#pragma unroll
        for (int j = 0; j < 4; ++j) {
            int rl = 16 * w + (l >> 4) * 4 + j;
            outl[rl * OST + colb] = f2b(acc[j] + bias_v);
        }
    }
    __syncthreads();
    // ---- coalesced global writes ----
    for (int i = tid; i < 64 * 16; i += 256) {
        int row = i >> 4, c4 = i & 15;
        size_t rg = blk * 64 + row;
        if (rg < NNODES)
            ((uint4*)bases)[rg * 16 + c4] = *(const uint4*)&outl[row * OST + c4 * 8];
    }
    for (int i = tid; i < 64 * 12; i += 256) {
        int row = i / 12, c4 = i % 12;
        size_t rg = blk * 64 + row;
        if (rg < NNODES)
            ((uint4*)wco)[rg * 12 + c4] = *(const uint4*)&outl[row * OST + BFD + c4 * 8];
    }
}

// 4. CSR aggregation + einsum + fused BN-stat partials. v6 + rowptr prefetch
//    (round-18 form — the measured-best variant: 117.6 us, 52 VGPR).
template <typename TW>
__global__ __launch_bounds__(256) void k_agg(const int* __restrict__ rowptr,
                                             const int* __restrict__ csr,
                                             const uint4* __restrict__ b4,
                                             const TW* __restrict__ wco,
                                             const float* __restrict__ bias,
                                             bf16* __restrict__ conv,
                                             float* __restrict__ partials) {
    __shared__ float agg[8][3][BFD];
    __shared__ float red[512];
    int tid = threadIdx.x;
    int g = tid >> 5, cl = tid & 31;
    int sub = cl >> 4;
    int ln16 = cl & 15;
    red[tid] = 0.f;
    red[tid + 256] = 0.f;
    __syncthreads();
    int hh = cl >> 2;
    int dbase = 8 * (cl & 3);
    float bb[8];
#pragma unroll
    for (int j = 0; j < 8; ++j) bb[j] = bias[8 * cl + j];
    float sts[8], sts2[8];
#pragma unroll
    for (int j = 0; j < 8; ++j) { sts[j] = 0.f; sts2[j] = 0.f; }
    int n0 = blockIdx.x * 8 + g;
    int pr0 = 0, pr1 = 0;
    if (n0 < NNODES) { pr0 = rowptr[n0]; pr1 = rowptr[n0 + 1]; }
    for (int n = n0; n < NNODES; n += AGGBLK * 8) {
        int r0 = pr0, r1 = pr1;
        int n2 = n + AGGBLK * 8;
        if (n2 < NNODES) { pr0 = rowptr[n2]; pr1 = rowptr[n2 + 1]; }
        float s0 = 0.f, s1 = 0.f, s2 = 0.f, s3 = 0.f;
        float s4 = 0.f, s5 = 0.f, s6 = 0.f, s7 = 0.f;
        float m0 = -INFINITY, m1 = -INFINITY, m2 = -INFINITY, m3 = -INFINITY;
        float m4 = -INFINITY, m5 = -INFINITY, m6 = -INFINITY, m7 = -INFINITY;
        int e = r0;
#define ACCU4(v) { float f0 = __uint_as_float((v).x << 16);            \
                   float f1 = __uint_as_float((v).x & 0xFFFF0000u);    \
                   float f2 = __uint_as_float((v).y << 16);            \
                   float f3 = __uint_as_float((v).y & 0xFFFF0000u);    \
                   float f4 = __uint_as_float((v).z << 16);            \
                   float f5 = __uint_as_float((v).z & 0xFFFF0000u);    \
                   float f6 = __uint_as_float((v).w << 16);            \
                   float f7 = __uint_as_float((v).w & 0xFFFF0000u);    \
                   s0 += f0; s1 += f1; s2 += f2; s3 += f3;             \
                   s4 += f4; s5 += f5; s6 += f6; s7 += f7;             \
                   m0 = fmaxf(m0, f0); m1 = fmaxf(m1, f1);             \
                   m2 = fmaxf(m2, f2); m3 = fmaxf(m3, f3);             \
                   m4 = fmaxf(m4, f4); m5 = fmaxf(m5, f5);             \
                   m6 = fmaxf(m6, f6); m7 = fmaxf(m7, f7); }
        for (; e + 8 <= r1; e += 8) {
            int i0 = csr[e + 0 + sub], i1 = csr[e + 2 + sub];
            int i2 = csr[e + 4 + sub], i3 = csr[e + 6 + sub];
            uint4 v0 = b4[(size_t)i0 * 16 + ln16];
            uint4 v1 = b4[(size_t)i1 * 16 + ln16];
            uint4 v2 = b4[(size_t)i2 * 16 + ln16];
            uint4 v3 = b4[(size_t)i3 * 16 + ln16];
            ACCU4(v0) ACCU4(v1) ACCU4(v2) ACCU4(v3)
        }
        for (; e + 2 <= r1; e += 2) {
            uint4 v = b4[(size_t)csr[e + sub] * 16 + ln16];
            ACCU4(v)
        }
        if (e < r1 && sub == 0) {
            uint4 v = b4[(size_t)csr[e] * 16 + ln16];
            ACCU4(v)
        }
#undef ACCU4
        s0 += __shfl_xor(s0, 16); s1 += __shfl_xor(s1, 16);
        s2 += __shfl_xor(s2, 16); s3 += __shfl_xor(s3, 16);
        s4 += __shfl_xor(s4, 16); s5 += __shfl_xor(s5, 16);
        s6 += __shfl_xor(s6, 16); s7 += __shfl_xor(s7, 16);
        m0 = fmaxf(m0, __shfl_xor(m0, 16)); m1 = fmaxf(m1, __shfl_xor(m1, 16));
        m2 = fmaxf(m2, __shfl_xor(m2, 16)); m3 = fmaxf(m3, __shfl_xor(m3, 16));
        m4 = fmaxf(m4, __shfl_xor(m4, 16)); m5 = fmaxf(m5, __shfl_xor(m5, 16));
        m6 = fmaxf(m6, __shfl_xor(m6, 16)); m7 = fmaxf(m7, __shfl_xor(m7, 16));
        if (sub == 0) {
            float inv = 1.0f / (float)(r1 - r0);
            int cb2 = ln16 * 8;
            *(float4*)&agg[g][0][cb2]     = make_float4(s0, s1, s2, s3);
            *(float4*)&agg[g][0][cb2 + 4] = make_float4(s4, s5, s6, s7);
            *(float4*)&agg[g][1][cb2]     = make_float4(s0 * inv, s1 * inv, s2 * inv, s3 * inv);
            *(float4*)&agg[g][1][cb2 + 4] = make_float4(s4 * inv, s5 * inv, s6 * inv, s7 * inv);
            *(float4*)&agg[g][2][cb2]     = make_float4(m0, m1, m2, m3);
            *(float4*)&agg[g][2][cb2 + 4] = make_float4(m4, m5, m6, m7);
        }
        const TW* wp = &wco[(size_t)n * NCOMB + hh * 12];
        float wv[12];
#pragma unroll
        for (int k = 0; k < 12; ++k) wv[k] = ldf(&wp[k]);
        float o[8];
#pragma unroll
        for (int j = 0; j < 8; ++j) {
            int d = dbase + j;
            float a = 0.f;
#pragma unroll
            for (int b = 0; b < 4; ++b) {
                a += wv[b] * agg[g][0][b * 32 + d];
                a += wv[4 + b] * agg[g][1][b * 32 + d];
                a += wv[8 + b] * agg[g][2][b * 32 + d];
            }
            a += bb[j];
            o[j] = a;
            sts[j] += a;
            sts2[j] += a * a;
        }
        uint4 cv = make_uint4(pack2bf(o[0], o[1]), pack2bf(o[2], o[3]),
                              pack2bf(o[4], o[5]), pack2bf(o[6], o[7]));
        ((uint4*)conv)[(size_t)n * 32 + cl] = cv;
    }
#pragma unroll
    for (int j = 0; j < 8; ++j) {
        atomicAdd(&red[8 * cl + j], sts[j]);
        atomicAdd(&red[256 + 8 * cl + j], sts2[j]);
    }
    __syncthreads();
    partials[(size_t)blockIdx.x * 512 + tid] = red[tid];
    partials[(size_t)blockIdx.x * 512 + 256 + tid] = red[tid + 256];
}

// 4b. reduce partials -> sums[512]
__global__ __launch_bounds__(256) void k_redstats(const float* __restrict__ partials,
                                                  float* __restrict__ sums) {
    int g = blockIdx.x * 256 + threadIdx.x;
    int j = g & 511;
    int chunk = g >> 9;
    float s = 0.f;
    for (int pb = chunk * 256; pb < (chunk + 1) * 256; ++pb)
        s += partials[(size_t)pb * 512 + j];
    atomicAdd(&sums[j], s);
}

// 6. BN finalize
template <int C>
__global__ void k_bnfin(const float* __restrict__ sums, const float* __restrict__ g,
                        const float* __restrict__ b, float nrows, float* __restrict__ ss) {
    int c = threadIdx.x;
    float mu = sums[c] / nrows;
    float var = sums[C + c] / nrows - mu * mu;
    float rstd = rsqrtf(fmaxf(var, 0.f) + EPSV);
    float sc = rstd * g[c];
    ss[c] = sc;
    ss[C + c] = b[c] - mu * sc;
}

// 8. pooling with FUSED final-layer BN-apply+ReLU+residual (verified form)
__global__ __launch_bounds__(256) void k_pool(const bf16* __restrict__ h,
                                              const bf16* __restrict__ conv,
                                              const float* __restrict__ ss,
                                              const int* __restrict__ batch,
                                              float* __restrict__ gs,
                                              float* __restrict__ cnt) {
    int c = threadIdx.x;
    float sc = ss[c], sb = ss[HIDC + c];
    int n0 = blockIdx.x * NPP;
    int end = min(n0 + NPP, NNODES);
    float acc = 0.f, ccnt = 0.f;
    int cur = batch[n0];
    for (int n = n0; n < end; ++n) {
        int b = batch[n];
        if (b != cur) {
            atomicAdd(&gs[(size_t)cur * HIDC + c], acc);
            if (c == 0) atomicAdd(&cnt[cur], ccnt);
            acc = 0.f; ccnt = 0.f; cur = b;
        }
        float v = b2f(conv[(size_t)n * HIDC + c]) * sc + sb;
        acc += b2f(h[(size_t)n * HIDC + c]) + fmaxf(v, 0.f);
        ccnt += 1.f;
    }
    atomicAdd(&gs[(size_t)cur * HIDC + c], acc);
    if (c == 0) atomicAdd(&cnt[cur], ccnt);
}

// 9. head GEMM + fused input transform + fused BN stats.
template <int K, int C, int FUSE>
__global__ __launch_bounds__(256) void k_gemmstats(const float* __restrict__ in,
                                                   const float* __restrict__ cnt,
                                                   const float* __restrict__ ssin,
                                                   const float* __restrict__ W,
                                                   float* __restrict__ out,
                                                   float* __restrict__ sums) {
    constexpr int RG = 256 / C;
    constexpr int RPT = RPBH / RG;
    __shared__ float rs[RPBH][K + 1];
    __shared__ float fac[RPBH];
    __shared__ float red[2][C];
    int tid = threadIdx.x;
    int r0 = blockIdx.x * RPBH;
    if (FUSE == 0 && tid < RPBH) fac[tid] = 1.f / fmaxf(cnt[r0 + tid], 1.f);
    if (tid < C) { red[0][tid] = 0.f; red[1][tid] = 0.f; }
    __syncthreads();
    for (int i = tid; i < RPBH * K; i += 256) {
        int r = i / K, k = i - r * K;
        float v = in[(size_t)(r0 + r) * K + k];
        if (FUSE == 0) v *= fac[r];
        else v = fmaxf(v * ssin[k] + ssin[K + k], 0.f);
        rs[r][k] = v;
    }
    __syncthreads();
    int c = tid % C;
    int g = tid / C;
    float acc[RPT];
#pragma unroll
    for (int j = 0; j < RPT; ++j) acc[j] = 0.f;
    for (int k = 0; k < K; ++k) {
        float w = W[k * C + c];
#pragma unroll
        for (int j = 0; j < RPT; ++j) acc[j] += rs[g * RPT + j][k] * w;
    }
    float s = 0.f, s2 = 0.f;
#pragma unroll
    for (int j = 0; j < RPT; ++j) {
        int r = g * RPT + j;
        out[(size_t)(r0 + r) * C + c] = acc[j];
        s += acc[j];
        s2 += acc[j] * acc[j];
    }
    atomicAdd(&red[0][c], s);
    atomicAdd(&red[1][c], s2);
    __syncthreads();
    if (tid < C) {
        atomicAdd(&sums[tid], red[0][tid]);
        atomicAdd(&sums[C + tid], red[1][tid]);
    }
}

// 12. final linear with fused BN2+ReLU
__global__ __launch_bounds__(256) void k_final2(const float* __restrict__ r2,
                                                const float* __restrict__ ss,
                                                const float* __restrict__ w3,
                                                const float* __restrict__ b3,
                                                float* __restrict__ out) {
    int r = blockIdx.x * 256 + threadIdx.x;
    if (r >= NGR) return;
    float acc = 0.f;
#pragma unroll
    for (int k = 0; k < 64; ++k) {
        float v = fmaxf(r2[r * 64 + k] * ss[k] + ss[64 + k], 0.f);
        acc += v * w3[k];
    }
    out[r] = acc + b3[0];
}

static inline size_t alignup(size_t v) { return (v + 255) & ~(size_t)255; }

static size_t carve_need(int E) {
    size_t off = 0;
    off = alignup(off + (size_t)NNODES * HIDC * 2);            // h bf16
    off = alignup(off + (size_t)NNODES * BFD * 2);             // bases bf16
    off = alignup(off + (size_t)NNODES * NCOMB * 2);           // wco bf16
    off = alignup(off + (size_t)NNODES * HIDC * 2);            // conv bf16
    off = alignup(off + (size_t)(NNODES + 1) * 4);             // rowptr
    off = alignup(off + (size_t)NNODES * 4);                   // cursor
    off = alignup(off + (size_t)E * 4);                        // csr
    off = alignup(off + (size_t)E * 8);                        // ebuf (pool aliases)
    off = alignup(off + 2 * HIDC * 4);                         // sums
    off = alignup(off + 2 * HIDC * 4);                         // ss
    off = alignup(off + 256 * 4);                              // btot
    off = alignup(off + 256 * 4);                              // boff
    off = alignup(off + 256 * 4);                              // gcur
    off = alignup(off + (size_t)LAYERSN * PBL * 8 * 2);        // Bp4
    off = alignup(off + (size_t)AGGBLK * 512 * 4);             // partials
    return off;
}

static void run_all(const int* x, const int* esrc, const int* edst, const int* batch,
                    const float* emb, const float* basesW, const float* combW,
                    const float* combB, const float* convB, const float* bnG,
                    const float* bnB, const float* w1, const float* bn1g,
                    const float* bn1b, const float* w2, const float* bn2g,
                    const float* bn2b, const float* w3, const float* b3, int E,
                    float* out, char* base, hipStream_t stream) {
    size_t off = 0;
    bf16* h = (bf16*)(base + off);     off = alignup(off + (size_t)NNODES * HIDC * 2);
    bf16* bases = (bf16*)(base + off); off = alignup(off + (size_t)NNODES * BFD * 2);
    bf16* wco = (bf16*)(base + off);   off = alignup(off + (size_t)NNODES * NCOMB * 2);
    bf16* conv = (bf16*)(base + off);  off = alignup(off + (size_t)NNODES * HIDC * 2);
    int* rowptr = (int*)(base + off);  off = alignup(off + (size_t)(NNODES + 1) * 4);
    int* cursor = (int*)(base + off);  off = alignup(off + (size_t)NNODES * 4);
    int* csr = (int*)(base + off);     off = alignup(off + (size_t)E * 4);
    size_t o_ebuf = off;
    uint2* ebuf = (uint2*)(base + off); off = alignup(off + (size_t)E * 8);
    float* sums = (float*)(base + off); off = alignup(off + 2 * HIDC * 4);
    float* ss = (float*)(base + off);   off = alignup(off + 2 * HIDC * 4);
    int* btot = (int*)(base + off);     off = alignup(off + 256 * 4);
    int* boff = (int*)(base + off);     off = alignup(off + 256 * 4);
    int* gcur = (int*)(base + off);     off = alignup(off + 256 * 4);
    bf16* Bp4 = (bf16*)(base + off);    off = alignup(off + (size_t)LAYERSN * PBL * 8 * 2);
    float* partials = (float*)(base + off); off = alignup(off + (size_t)AGGBLK * 512 * 4);
    size_t po = o_ebuf;
    float* gs = (float*)(base + po);  po = alignup(po + (size_t)NGR * HIDC * 4);
    float* cnt = (float*)(base + po); po = alignup(po + (size_t)NGR * 4);
    float* r1 = (float*)(base + po);  po = alignup(po + (size_t)NGR * 128 * 4);
    float* r2 = (float*)(base + po);  po = alignup(po + (size_t)NGR * 64 * 4);

    const int NB = (NNODES + SCHUNK - 1) / SCHUNK;  // 98
    const int GEMMBLK = (NNODES + 63) / 64;         // 1563

    // once: CSR build (bucketed) + all-layer weight pack
    k_packB4<<<(LAYERSN * PBL + 255) / 256, 256, 0, stream>>>(basesW, combW, Bp4);
    hipMemsetAsync(cursor, 0, (size_t)NNODES * 4, stream);
    k_hist<<<(E + 255) / 256, 256, 0, stream>>>(edst, cursor, E);
    k_scansum<<<NB, 256, 0, stream>>>(cursor, btot, NNODES);
    k_scansmall<<<1, 64, 0, stream>>>(btot, boff, NB);
    k_scanapply<<<NB, 256, 0, stream>>>(cursor, boff, rowptr, cursor, NNODES);
    k_binit<<<1, NBUK, 0, stream>>>(rowptr, gcur);
    k_bucket<<<(E + 1023) / 1024, 256, 0, stream>>>(esrc, edst, gcur, ebuf, E);
    k_scatter2<<<NBUK * SC2K, 256, 0, stream>>>(ebuf, rowptr, cursor, csr);

    for (int l = 0; l < LAYERSN; ++l) {
        hipMemsetAsync(sums, 0, 2 * HIDC * 4, stream);
        if (l == 0) {
            k_gemm_mfma<0><<<GEMMBLK, 256, 0, stream>>>(
                h, Bp4, combB, bases, wco, nullptr, ss, x, emb);
        } else {
            k_gemm_mfma<1><<<GEMMBLK, 256, 0, stream>>>(
                h, Bp4 + (size_t)l * PBL * 8, combB + (size_t)l * NCOMB, bases, wco,
                conv, ss, nullptr, nullptr);
        }
        k_agg<bf16><<<AGGBLK, 256, 0, stream>>>(rowptr, csr, (const uint4*)bases,
                                                wco, convB + (size_t)l * HIDC, conv,
                                                partials);
        k_redstats<<<16, 256, 0, stream>>>(partials, sums);
        k_bnfin<HIDC><<<1, HIDC, 0, stream>>>(sums, bnG + (size_t)l * HIDC,
                                              bnB + (size_t)l * HIDC, (float)NNODES, ss);
    }

    hipMemsetAsync(gs, 0, (size_t)NGR * HIDC * 4, stream);
    hipMemsetAsync(cnt, 0, (size_t)NGR * 4, stream);
    k_pool<<<(NNODES + NPP - 1) / NPP, 256, 0, stream>>>(h, conv, ss, batch, gs, cnt);

    hipMemsetAsync(sums, 0, 2 * HIDC * 4, stream);
    k_gemmstats<256, 128, 0><<<NGR / RPBH, 256, 0, stream>>>(gs, cnt, nullptr, w1, r1, sums);
    k_bnfin<128><<<1, 128, 0, stream>>>(sums, bn1g, bn1b, (float)NGR, ss);
    hipMemsetAsync(sums, 0, 2 * HIDC * 4, stream);
    k_gemmstats<128, 64, 1><<<NGR / RPBH, 256, 0, stream>>>(r1, nullptr, ss, w2, r2, sums);
    k_bnfin<64><<<1, 64, 0, stream>>>(sums, bn2g, bn2b, (float)NGR, ss);
    k_final2<<<(NGR + 255) / 256, 256, 0, stream>>>(r2, ss, w3, b3, out);
}

extern "C" void kernel_launch(void* const* d_in, const int* in_sizes, int n_in,
                              void* d_out, int out_size, void* d_ws, size_t ws_size,
                              hipStream_t stream) {
    const int* x        = (const int*)d_in[0];
    const int* esrc     = (const int*)d_in[1];
    const int* edst     = (const int*)d_in[2];
    const int* batch    = (const int*)d_in[3];
    const float* emb    = (const float*)d_in[4];
    const float* basesW = (const float*)d_in[5];
    const float* combW  = (const float*)d_in[6];
    const float* combB  = (const float*)d_in[7];
    const float* convB  = (const float*)d_in[8];
    const float* bnG    = (const float*)d_in[9];
    const float* bnB    = (const float*)d_in[10];
    const float* w1     = (const float*)d_in[11];
    const float* bn1g   = (const float*)d_in[12];
    const float* bn1b   = (const float*)d_in[13];
    const float* w2     = (const float*)d_in[14];
    const float* bn2g   = (const float*)d_in[15];
    const float* bn2b   = (const float*)d_in[16];
    const float* w3     = (const float*)d_in[17];
    const float* b3     = (const float*)d_in[18];
    const int E = in_sizes[1];

    size_t need = carve_need(E);   // ~155 MB
    if (ws_size >= need) {
        run_all(x, esrc, edst, batch, emb, basesW, combW, combB, convB,
                bnG, bnB, w1, bn1g, bn1b, w2, bn2g, bn2b, w3, b3, E,
                (float*)d_out, (char*)d_ws, stream);
    } else {
        k_sentinel<<<(out_size + 255) / 256, 256, 0, stream>>>(
            (float*)d_out, out_size, (float)(ws_size >> 20));
    }
}